// Round 15
// baseline (274.119 us; speedup 1.0000x reference)
//
#include <hip/hip_runtime.h>
#include <math.h>

constexpr int EMBED  = 1024;
constexpr int NHEADS = 16;
constexpr int HDIM   = 64;
constexpr int BATCH  = 2;
constexpr int SEQ    = 2048;
constexpr int MROWS  = BATCH * SEQ;  // 4096

typedef unsigned short u16b;  // bf16 storage
typedef __attribute__((ext_vector_type(8))) short bfrag;   // 8 bf16 (4 VGPRs)
typedef __attribute__((ext_vector_type(4))) float ffrag;   // 4 fp32 acc
typedef __attribute__((ext_vector_type(16))) float f16frag; // 16 fp32 acc (32x32)
typedef __attribute__((ext_vector_type(4))) int i32x4;

// softmax scale folded with log2(e): exp(0.125*x) == exp2(0.18033688*x)
#define SCALE_Q 0.18033688f

__device__ __forceinline__ u16b f2b(float f) {          // RNE
    union { float f; unsigned u; } v; v.f = f;
    unsigned r = v.u + 0x7fffu + ((v.u >> 16) & 1u);
    return (u16b)(r >> 16);
}

__device__ __forceinline__ unsigned cvtpk_bf16(float a, float b) {
    unsigned r;
    asm("v_cvt_pk_bf16_f32 %0, %1, %2" : "=v"(r) : "v"(a), "v"(b));
    return r;
}

// permlane32_swap wrapper: returns {this_lane_word, swapped_word} as ints
__device__ __forceinline__ void plane_swap(unsigned a, unsigned b, int& lo, int& hi) {
    auto r = __builtin_amdgcn_permlane32_swap((int)a, (int)b, false, false);
    lo = (int)r[0];
    hi = (int)r[1];
}

__device__ __forceinline__ void gload_lds16(const u16b* g, u16b* l) {
    __builtin_amdgcn_global_load_lds(
        (const __attribute__((address_space(1))) void*)g,
        (__attribute__((address_space(3))) void*)l,
        16, 0, 0);
}

template<int N>
__device__ __forceinline__ void wait_vmcnt() {
    if constexpr (N == 0)      asm volatile("s_waitcnt vmcnt(0)" ::: "memory");
    else if constexpr (N == 2) asm volatile("s_waitcnt vmcnt(2)" ::: "memory");
    else if constexpr (N == 3) asm volatile("s_waitcnt vmcnt(3)" ::: "memory");
    else if constexpr (N == 4) asm volatile("s_waitcnt vmcnt(4)" ::: "memory");
    else static_assert(N == 0 || N == 2 || N == 3 || N == 4, "unsupported vmcnt");
}

struct GemmPtrs {
    const u16b* A[3];
    const u16b* B[3];
    const float* D[3];
    u16b* Cb[3];
    float* Cf[3];
    float scale[3];
    int vt[3];       // epilogue writes [B,H,64,S] (V-transposed)
    int hs[3];       // epilogue writes [B,H,S,64] (head-split)
};

// ---------- unified prep: z 0..2 inputs (convert), z 3..6 weights ----------
__global__ void prep_all(const float* __restrict__ q, const float* __restrict__ k,
                         const float* __restrict__ v,
                         const float* __restrict__ Wq, const float* __restrict__ Wk,
                         const float* __restrict__ Wv, const float* __restrict__ Wo,
                         u16b* __restrict__ oq, u16b* __restrict__ ok, u16b* __restrict__ ov,
                         u16b* __restrict__ wq, u16b* __restrict__ wk,
                         u16b* __restrict__ wv, u16b* __restrict__ wo,
                         u16b* __restrict__ wqt, u16b* __restrict__ wkt) {
    const int z = blockIdx.z;
    const int tid = threadIdx.x;
    if (z < 3) {
        const float* src = (z == 0) ? q : (z == 1) ? k : v;
        u16b* dst = (z == 0) ? oq : (z == 1) ? ok : ov;
        const int i = blockIdx.x * 256 + tid;
        float4 val = ((const float4*)src)[i];
        ushort4 o;
        o.x = f2b(val.x); o.y = f2b(val.y); o.z = f2b(val.z); o.w = f2b(val.w);
        ((ushort4*)dst)[i] = o;
        return;
    }
    if (blockIdx.x >= 1024) return;
    const int w = z - 3;
    const float* src = (w == 0) ? Wq : (w == 1) ? Wk : (w == 2) ? Wv : Wo;
    u16b* dst  = (w == 0) ? wq : (w == 1) ? wk : (w == 2) ? wv : wo;
    u16b* dstT = (w == 0) ? wqt : (w == 1) ? wkt : nullptr;
    __shared__ float t[32][33];
    const int bx = (blockIdx.x & 31) * 32, by = (blockIdx.x >> 5) * 32;
    const int x = tid & 31, y = tid >> 5;  // 32x8
#pragma unroll
    for (int r = 0; r < 4; ++r) {
        const int row = by + y + 8 * r;
        const float val = src[(size_t)row * EMBED + bx + x];
        dst[(size_t)row * EMBED + bx + x] = f2b(val);
        if (w < 2) t[y + 8 * r][x] = val;
    }
    if (w >= 2) return;
    __syncthreads();
#pragma unroll
    for (int r = 0; r < 4; ++r)
        dstT[(size_t)(bx + y + 8 * r) * EMBED + by + x] = f2b(t[x][y + 8 * r]);
}

// ---------- BM x BN bf16 MFMA NT GEMM, depth-2 prefetch + counted vmcnt ----------
// MODE 0: Cb = f2b(scale*AB)  (vt: [B,H,64,S] layout; hs: [B,H,S,64] layout)
// MODE 1: Cb = f2b(D - AB)
// MODE 2: Cf = AB (fp32)
template<int MODE, int BM, int BN>
__global__ __launch_bounds__(256) void gemm_big(GemmPtrs p, int M, int N, int K) {
    const int z = blockIdx.z;
    const u16b* __restrict__ A = p.A[z];
    const u16b* __restrict__ B = p.B[z];
    const float* __restrict__ D = p.D[z];
    u16b* __restrict__ Cb = p.Cb[z];
    float* __restrict__ Cf = p.Cf[z];
    const float scale = p.scale[z];
    const int vt = p.vt[z], hs = p.hs[z];

    constexpr int BK = 32;
    constexpr int IT = BM / 32;       // i-tiles per wave
    constexpr int JT = BN / 32;       // j-tiles per wave
    constexpr int IA = BM / 64;       // A staging issues per wave
    constexpr int IB = BN / 64;       // B staging issues per wave
    constexpr int LPW = IA + IB;      // per-wave loads per STAGE (vmcnt unit)
    __shared__ __align__(16) u16b As[2][BM * BK];
    __shared__ __align__(16) u16b Bs[2][BN * BK];

    const int tid = threadIdx.x;
    const int wave = tid >> 6, lane = tid & 63;
    const int quad = lane >> 4, l16 = lane & 15;
    const int wrow = wave >> 1, wcol = wave & 1;
    const int m0 = blockIdx.y * BM, n0 = blockIdx.x * BN;

    ffrag acc[IT][JT];
#pragma unroll
    for (int i = 0; i < IT; ++i)
#pragma unroll
        for (int j = 0; j < JT; ++j) acc[i][j] = ffrag{0.f, 0.f, 0.f, 0.f};

    const int srow = lane >> 2, schunk = lane & 3;

    // stage K-tile kt into buffer buf (LPW global_load_lds per wave)
    auto STAGE = [&](int buf, int kt) {
#pragma unroll
        for (int q = 0; q < IA; ++q) {
            int row = wave * (BM / 4) + q * 16;
            gload_lds16(A + (size_t)(m0 + row + srow) * K + kt + schunk * 8,
                        &As[buf][row * BK]);
        }
#pragma unroll
        for (int q = 0; q < IB; ++q) {
            int row = wave * (BN / 4) + q * 16;
            gload_lds16(B + (size_t)(n0 + row + srow) * K + kt + schunk * 8,
                        &Bs[buf][row * BK]);
        }
    };

    // prologue: tiles 0 and 1 in flight; wait only for tile 0
    STAGE(0, 0);
    STAGE(1, BK);
    wait_vmcnt<LPW>();
    __builtin_amdgcn_s_barrier();
    __builtin_amdgcn_sched_barrier(0);

    int cur = 0;
    for (int kt = 0; kt < K; kt += BK, cur ^= 1) {
        // 1) LDS -> regs for tile cur
        bfrag af[IT], bfv[JT];
#pragma unroll
        for (int i = 0; i < IT; ++i)
            af[i] = *(const bfrag*)&As[cur][(wrow * (BM / 2) + i * 16 + l16) * BK + quad * 8];
#pragma unroll
        for (int j = 0; j < JT; ++j)
            bfv[j] = *(const bfrag*)&Bs[cur][(wcol * (BN / 2) + j * 16 + l16) * BK + quad * 8];
        asm volatile("s_waitcnt lgkmcnt(0)" ::: "memory");
        __builtin_amdgcn_sched_barrier(0);
        __builtin_amdgcn_s_barrier();          // all waves done reading [cur]
        __builtin_amdgcn_sched_barrier(0);

        // 2) refill [cur] with tile t+2 (stays in flight across barriers)
        const bool stage = (kt + 2 * BK < K);
        if (stage) STAGE(cur, kt + 2 * BK);

        // 3) compute on regs — covers tile t+1's remaining latency
#pragma unroll
        for (int i = 0; i < IT; ++i)
#pragma unroll
            for (int j = 0; j < JT; ++j)
                acc[i][j] = __builtin_amdgcn_mfma_f32_16x16x32_bf16(af[i], bfv[j], acc[i][j], 0, 0, 0);

        // 4) tile t+1 (issued a full K-step ago) must be resident
        if (stage) wait_vmcnt<LPW>();
        else       wait_vmcnt<0>();
        __builtin_amdgcn_s_barrier();
        __builtin_amdgcn_sched_barrier(0);
    }

    if (MODE == 0 && vt) {
#pragma unroll
        for (int i = 0; i < IT; ++i)
#pragma unroll
            for (int j = 0; j < JT; ++j) {
                const int col = n0 + wcol * (BN / 2) + j * 16 + l16;
                const int h = col >> 6, d = col & 63;
                const int row0 = m0 + wrow * (BM / 2) + i * 16 + quad * 4;
                const int b = row0 >> 11, s = row0 & 2047;
                ushort4 o;
                o.x = f2b(acc[i][j][0]); o.y = f2b(acc[i][j][1]);
                o.z = f2b(acc[i][j][2]); o.w = f2b(acc[i][j][3]);
                *(ushort4*)&Cb[((size_t)(b * NHEADS + h) * HDIM + d) * SEQ + s] = o;
            }
        return;
    }
    if (MODE == 0 && hs) {
#pragma unroll
        for (int i = 0; i < IT; ++i)
#pragma unroll
        for (int j = 0; j < JT; ++j) {
                const int col = n0 + wcol * (BN / 2) + j * 16 + l16;
                const int h = col >> 6, d = col & 63;
                const int row0 = m0 + wrow * (BM / 2) + i * 16 + quad * 4;
                const int b = row0 >> 11, s0 = row0 & 2047;
#pragma unroll
                for (int r = 0; r < 4; ++r)
                    Cb[((size_t)(b * NHEADS + h) * SEQ + s0 + r) * HDIM + d] =
                        f2b(acc[i][j][r] * scale);
            }
        return;
    }

#pragma unroll
    for (int i = 0; i < IT; ++i)
#pragma unroll
        for (int j = 0; j < JT; ++j) {
            const int col = n0 + wcol * (BN / 2) + j * 16 + l16;
#pragma unroll
            for (int r = 0; r < 4; ++r) {
                const int row = m0 + wrow * (BM / 2) + i * 16 + quad * 4 + r;
                const size_t idx = (size_t)row * N + col;
                const float v = acc[i][j][r];
                if (MODE == 0) Cb[idx] = f2b(v * scale);
                else if (MODE == 1) Cb[idx] = f2b(D[idx] - v);
                else Cf[idx] = v;
            }
        }
}

// ---------- flash attention v6b: v6 + s_setprio around MFMA clusters ----------
// qp,kp: [B,H,S,64] bf16 (q pre-scaled); Vt: [B,H,64,S].
// blockIdx.z: b = z>>1, split = z&1. Each block handles 1024 keys.
// VERIFIED v6 at 59.0 us (round 14). LDS staging is the coalescing layer: the
// no-LDS variant (v7, round 12) hit uncoalesced 128B-stride fragment loads
// and regressed to 131 us. Do not remove LDS here.
// v6b: T5 setprio(1) around QK^T and PV MFMA clusters — waves diverge between
// barriers (softmax VALU vs MFMA), so the CU scheduler has roles to arbitrate.
__global__ __launch_bounds__(256) void flash_attn6(
    const u16b* __restrict__ Qp, const u16b* __restrict__ Kp,
    const u16b* __restrict__ Vt, float* __restrict__ Opart,
    float* __restrict__ Lpart)
{
    const int tid = threadIdx.x;
    const int wave = tid >> 6, lane = tid & 63;
    const int l32 = lane & 31, hi = lane >> 5;
    const int qt = blockIdx.x, h = blockIdx.y;
    const int b = blockIdx.z >> 1, sp = blockIdx.z & 1;
    const int qb = qt * 128 + wave * 32;
    const int kt0 = sp * (SEQ / 2), kt1 = kt0 + SEQ / 2;

    __shared__ __align__(16) u16b Ks[2][64 * 64];    // [key][d], swizzled
    __shared__ __align__(16) u16b Vs[2][64 * 64];    // [d][key], swizzled

    const size_t hsbase = (size_t)(b * NHEADS + h) * SEQ;
    const size_t vtbase = (size_t)(b * NHEADS + h) * HDIM * SEQ;
    const size_t obase  = ((size_t)sp * MROWS + (size_t)b * SEQ) * EMBED + h * HDIM;

    // Q fragments: B-operand of 32x32x16 (col=q=l32, k = ks*16 + hi*8 + j)
    bfrag bq[4];
#pragma unroll
    for (int ks = 0; ks < 4; ++ks)
        bq[ks] = *(const bfrag*)&Qp[(hsbase + qb + l32) * HDIM + ks * 16 + hi * 8];

    f16frag ov0, ov1;   // O^T rows d=0..31 / 32..63, col q=l32
#pragma unroll
    for (int r = 0; r < 16; ++r) { ov0[r] = 0.f; ov1[r] = 0.f; }
    float l_run = 0.f;

    const int r0 = tid >> 3, c0 = tid & 7;
    const int sw0 = (r0 * 8 + (c0 ^ (r0 & 7))) * 8;
    const int sw1 = ((r0 + 32) * 8 + (c0 ^ (r0 & 7))) * 8;
    const u16b* kgb = Kp + hsbase * HDIM;
    const u16b* vgb = Vt + vtbase;

    // stage first tile -> buf 0
    {
        const u16b* kg = kgb + (size_t)kt0 * HDIM;
        bfrag k0 = *(const bfrag*)(kg + tid * 8);
        bfrag k1 = *(const bfrag*)(kg + (tid + 256) * 8);
        bfrag v0 = *(const bfrag*)(vgb + (size_t)r0 * SEQ + kt0 + c0 * 8);
        bfrag v1 = *(const bfrag*)(vgb + (size_t)(r0 + 32) * SEQ + kt0 + c0 * 8);
        *(bfrag*)&Ks[0][sw0] = k0;  *(bfrag*)&Ks[0][sw1] = k1;
        *(bfrag*)&Vs[0][sw0] = v0;  *(bfrag*)&Vs[0][sw1] = v1;
    }
    __syncthreads();

    int p = 0;
    for (int kt = kt0; kt < kt1; kt += 64, p ^= 1) {
        const bool more = (kt + 64) < kt1;
        bfrag kn0, kn1, vn0, vn1;
        if (more) {
            const u16b* kg = kgb + (size_t)(kt + 64) * HDIM;
            kn0 = *(const bfrag*)(kg + tid * 8);
            kn1 = *(const bfrag*)(kg + (tid + 256) * 8);
            vn0 = *(const bfrag*)(vgb + (size_t)r0 * SEQ + kt + 64 + c0 * 8);
            vn1 = *(const bfrag*)(vgb + (size_t)(r0 + 32) * SEQ + kt + 64 + c0 * 8);
        }

        // --- S^T = K Q^T : two 32x32 tiles (keys 0-31, 32-63) ---
        f16frag St0, St1;
#pragma unroll
        for (int r = 0; r < 16; ++r) { St0[r] = 0.f; St1[r] = 0.f; }
        __builtin_amdgcn_s_setprio(1);
#pragma unroll
        for (int ks = 0; ks < 4; ++ks) {
            const int ch = ks * 2 + hi;
            bfrag k0 = *(const bfrag*)&Ks[p][(l32 * 8 + (ch ^ (l32 & 7))) * 8];
            bfrag k1 = *(const bfrag*)&Ks[p][((32 + l32) * 8 + (ch ^ (l32 & 7))) * 8];
            St0 = __builtin_amdgcn_mfma_f32_32x32x16_bf16(k0, bq[ks], St0, 0, 0, 0);
            St1 = __builtin_amdgcn_mfma_f32_32x32x16_bf16(k1, bq[ks], St1, 0, 0, 0);
        }
        __builtin_amdgcn_s_setprio(0);

        // --- max-free softmax: exp2 all, column sum for q=l32 ---
        // two accumulators break the 16-deep dependent add chain
        float rs0 = 0.f, rs1 = 0.f;
#pragma unroll
        for (int r = 0; r < 16; ++r) {
            const float a = __builtin_amdgcn_exp2f(St0[r]);
            const float c = __builtin_amdgcn_exp2f(St1[r]);
            St0[r] = a; St1[r] = c;
            rs0 += a; rs1 += c;
        }
        float rs = rs0 + rs1;
        rs += __shfl_xor(rs, 32);
        l_run += rs;

        // --- P -> bf16 B-operands fully in-register ---
        unsigned d0[8], d1[8];
#pragma unroll
        for (int rr = 0; rr < 8; ++rr) {
            d0[rr] = cvtpk_bf16(St0[2 * rr], St0[2 * rr + 1]);
            d1[rr] = cvtpk_bf16(St1[2 * rr], St1[2 * rr + 1]);
        }
        bfrag bp[4];
        {
            int a0, a1, b0, b1, c0w, c1, e0, e1;
            plane_swap(d0[0], d0[2], a0, a1);
            plane_swap(d0[1], d0[3], b0, b1);
            i32x4 w = { a0, b0, a1, b1 };
            bp[0] = __builtin_bit_cast(bfrag, w);
            plane_swap(d0[4], d0[6], c0w, c1);
            plane_swap(d0[5], d0[7], e0, e1);
            i32x4 w2 = { c0w, e0, c1, e1 };
            bp[1] = __builtin_bit_cast(bfrag, w2);
        }
        {
            int a0, a1, b0, b1, c0w, c1, e0, e1;
            plane_swap(d1[0], d1[2], a0, a1);
            plane_swap(d1[1], d1[3], b0, b1);
            i32x4 w = { a0, b0, a1, b1 };
            bp[2] = __builtin_bit_cast(bfrag, w);
            plane_swap(d1[4], d1[6], c0w, c1);
            plane_swap(d1[5], d1[7], e0, e1);
            i32x4 w2 = { c0w, e0, c1, e1 };
            bp[3] = __builtin_bit_cast(bfrag, w2);
        }

        // --- O^T += V^T P : two 32x32 d-tiles x 4 key-steps of 16 ---
        __builtin_amdgcn_s_setprio(1);
#pragma unroll
        for (int ks = 0; ks < 4; ++ks) {
            const int ch = ks * 2 + hi;
            bfrag v0 = *(const bfrag*)&Vs[p][(l32 * 8 + (ch ^ (l32 & 7))) * 8];
            bfrag v1 = *(const bfrag*)&Vs[p][((32 + l32) * 8 + (ch ^ (l32 & 7))) * 8];
            ov0 = __builtin_amdgcn_mfma_f32_32x32x16_bf16(v0, bp[ks], ov0, 0, 0, 0);
            ov1 = __builtin_amdgcn_mfma_f32_32x32x16_bf16(v1, bp[ks], ov1, 0, 0, 0);
        }
        __builtin_amdgcn_s_setprio(0);

        if (more) {
            *(bfrag*)&Ks[p ^ 1][sw0] = kn0;  *(bfrag*)&Ks[p ^ 1][sw1] = kn1;
            *(bfrag*)&Vs[p ^ 1][sw0] = vn0;  *(bfrag*)&Vs[p ^ 1][sw1] = vn1;
            __syncthreads();
        }
    }

    // epilogue: raw partial O (fp32) + partial l
    const size_t orow = obase + (size_t)(qb + l32) * EMBED;
#pragma unroll
    for (int rr = 0; rr < 4; ++rr) {
        float4 o0, o1;
        o0.x = ov0[4 * rr + 0]; o0.y = ov0[4 * rr + 1];
        o0.z = ov0[4 * rr + 2]; o0.w = ov0[4 * rr + 3];
        o1.x = ov1[4 * rr + 0]; o1.y = ov1[4 * rr + 1];
        o1.z = ov1[4 * rr + 2]; o1.w = ov1[4 * rr + 3];
        *(float4*)&Opart[orow + rr * 8 + hi * 4] = o0;
        *(float4*)&Opart[orow + 32 + rr * 8 + hi * 4] = o1;
    }
    if (hi == 0)
        Lpart[((size_t)sp * BATCH * NHEADS + b * NHEADS + h) * SEQ + qb + l32] = l_run;
}

// ---------- combine split-K partials -> ao bf16 [B,S,E] ----------
__global__ void combine_o(const float* __restrict__ O0, const float* __restrict__ O1,
                          const float* __restrict__ L0, const float* __restrict__ L1,
                          u16b* __restrict__ ao) {
    const int i = blockIdx.x * 256 + threadIdx.x;   // float4 index (1M total)
    const int e0 = i << 2;
    const int row = e0 >> 10, col = e0 & 1023;
    const int lidx = ((row >> 11) * NHEADS + (col >> 6)) * SEQ + (row & 2047);
    float4 a = ((const float4*)O0)[i];
    float4 c = ((const float4*)O1)[i];
    const float inv = 1.f / (L0[lidx] + L1[lidx]);
    ushort4 o;
    o.x = f2b((a.x + c.x) * inv); o.y = f2b((a.y + c.y) * inv);
    o.z = f2b((a.z + c.z) * inv); o.w = f2b((a.w + c.w) * inv);
    ((ushort4*)ao)[i] = o;
}

// ---------- launch ----------
extern "C" void kernel_launch(void* const* d_in, const int* in_sizes, int n_in,
                              void* d_out, int out_size, void* d_ws, size_t ws_size,
                              hipStream_t stream) {
    const float* query = (const float*)d_in[0];
    const float* key_  = (const float*)d_in[1];
    const float* value = (const float*)d_in[2];
    const float* Wq    = (const float*)d_in[3];
    const float* Wk    = (const float*)d_in[4];
    const float* Wv    = (const float*)d_in[5];
    const float* Wo    = (const float*)d_in[6];
    float* out = (float*)d_out;

    char* ws = (char*)d_ws;
    const size_t MB = 1024 * 1024;
    u16b* xq  = (u16b*)(ws + 0 * MB);    // 8 MB, dead after proj
    u16b* xk  = (u16b*)(ws + 8 * MB);    // dead after proj
    u16b* xv  = (u16b*)(ws + 16 * MB);   // dead after proj
    u16b* wq  = (u16b*)(ws + 24 * MB);   // dead after orth
    u16b* wk  = (u16b*)(ws + 26 * MB);   // dead after orth
    u16b* wv  = (u16b*)(ws + 28 * MB);   // dead after proj
    u16b* gq  = (u16b*)(ws + 32 * MB);   // dead after orth
    u16b* gk  = (u16b*)(ws + 34 * MB);   // dead after orth
    u16b* wqo = (u16b*)(ws + 36 * MB);   // dead after proj
    u16b* wko = (u16b*)(ws + 38 * MB);   // dead after proj
    u16b* wo  = (u16b*)(ws + 40 * MB);   // live until out-proj
    u16b* qp  = (u16b*)(ws + 44 * MB);   // [B,H,S,64], dead after attn
    u16b* kp  = (u16b*)(ws + 52 * MB);   // dead after attn
    u16b* Vt  = (u16b*)(ws + 60 * MB);   // [B,H,64,S], dead after attn
    u16b* wqt = (u16b*)(ws + 60 * MB);   // inside Vt region: dead after gram, Vt written later
    u16b* wkt = (u16b*)(ws + 62 * MB);
    float* Op  = (float*)(ws + 0 * MB);  // 2 x 16 MB fp32 [split][B,S,E] @ 0..32
    float* Lp  = (float*)(ws + 32 * MB); // 2 x 256 KB [split][B,H,S]
    u16b*  ao  = (u16b*)(ws + 44 * MB);  // combine output over dead qp

    // 1) unified prep (inputs + weights)
    prep_all<<<dim3(MROWS * EMBED / 1024, 1, 7), dim3(256), 0, stream>>>(
        query, key_, value, Wq, Wk, Wv, Wo,
        xq, xk, xv, wq, wk, wv, wo, wqt, wkt);

    // 2) Grams (z-batched): gq = Wq^T Wq, gk = Wk^T Wk  (64x64 tiles, 512 blocks)
    {
        GemmPtrs p{};
        p.A[0] = wqt; p.B[0] = wqt; p.Cb[0] = gq; p.scale[0] = 1.f;
        p.A[1] = wkt; p.B[1] = wkt; p.Cb[1] = gk; p.scale[1] = 1.f;
        gemm_big<0, 64, 64><<<dim3(EMBED / 64, EMBED / 64, 2), dim3(256), 0, stream>>>(
            p, EMBED, EMBED, EMBED);
    }
    // 3) Orth (z-batched): wqo = Wq - Wq*gk, wko = Wk - Wk*gq
    {
        GemmPtrs p{};
        p.A[0] = wq; p.B[0] = gk; p.D[0] = Wq; p.Cb[0] = wqo;
        p.A[1] = wk; p.B[1] = gq; p.D[1] = Wk; p.Cb[1] = wko;
        gemm_big<1, 64, 64><<<dim3(EMBED / 64, EMBED / 64, 2), dim3(256), 0, stream>>>(
            p, EMBED, EMBED, EMBED);
    }
    // 4) Projections (z-batched): q,k head-split; V transposed
    {
        GemmPtrs p{};
        p.A[0] = xq; p.B[0] = wqo; p.Cb[0] = qp; p.scale[0] = SCALE_Q; p.hs[0] = 1;
        p.A[1] = xk; p.B[1] = wko; p.Cb[1] = kp; p.scale[1] = 1.f;     p.hs[1] = 1;
        p.A[2] = xv; p.B[2] = wv;  p.Cb[2] = Vt; p.scale[2] = 1.f;     p.vt[2] = 1;
        gemm_big<0, 128, 128><<<dim3(EMBED / 128, MROWS / 128, 3), dim3(256), 0, stream>>>(
            p, MROWS, EMBED, EMBED);
    }
    // 5) Attention, split-K=2 (1024 blocks)
    flash_attn6<<<dim3(SEQ / 128, NHEADS, BATCH * 2), dim3(256), 0, stream>>>(
        qp, kp, Vt, Op, Lp);
    // 6) Combine partials -> ao
    combine_o<<<dim3(MROWS * EMBED / 1024), dim3(256), 0, stream>>>(
        Op, Op + (size_t)MROWS * EMBED, Lp, Lp + (size_t)BATCH * NHEADS * SEQ, ao);
    // 7) Output projection (fp32 out), BM=64 for 512-block occupancy
    {
        GemmPtrs p{};
        p.A[0] = ao; p.B[0] = wo; p.Cf[0] = out; p.scale[0] = 1.f;
        gemm_big<2, 64, 128><<<dim3(EMBED / 128, MROWS / 64, 1), dim3(256), 0, stream>>>(
            p, MROWS, EMBED, EMBED);
    }
}

// Round 16
// 272.640 us; speedup vs baseline: 1.0054x; 1.0054x over previous
//
#include <hip/hip_runtime.h>
#include <math.h>

constexpr int EMBED  = 1024;
constexpr int NHEADS = 16;
constexpr int HDIM   = 64;
constexpr int BATCH  = 2;
constexpr int SEQ    = 2048;
constexpr int MROWS  = BATCH * SEQ;  // 4096

typedef unsigned short u16b;  // bf16 storage
typedef __attribute__((ext_vector_type(8))) short bfrag;   // 8 bf16 (4 VGPRs)
typedef __attribute__((ext_vector_type(4))) float ffrag;   // 4 fp32 acc
typedef __attribute__((ext_vector_type(16))) float f16frag; // 16 fp32 acc (32x32)
typedef __attribute__((ext_vector_type(4))) int i32x4;

// softmax scale folded with log2(e): exp(0.125*x) == exp2(0.18033688*x)
#define SCALE_Q 0.18033688f

__device__ __forceinline__ u16b f2b(float f) {          // RNE
    union { float f; unsigned u; } v; v.f = f;
    unsigned r = v.u + 0x7fffu + ((v.u >> 16) & 1u);
    return (u16b)(r >> 16);
}

__device__ __forceinline__ unsigned cvtpk_bf16(float a, float b) {
    unsigned r;
    asm("v_cvt_pk_bf16_f32 %0, %1, %2" : "=v"(r) : "v"(a), "v"(b));
    return r;
}

// permlane32_swap wrapper: returns {this_lane_word, swapped_word} as ints
__device__ __forceinline__ void plane_swap(unsigned a, unsigned b, int& lo, int& hi) {
    auto r = __builtin_amdgcn_permlane32_swap((int)a, (int)b, false, false);
    lo = (int)r[0];
    hi = (int)r[1];
}

__device__ __forceinline__ void gload_lds16(const u16b* g, u16b* l) {
    __builtin_amdgcn_global_load_lds(
        (const __attribute__((address_space(1))) void*)g,
        (__attribute__((address_space(3))) void*)l,
        16, 0, 0);
}

template<int N>
__device__ __forceinline__ void wait_vmcnt() {
    if constexpr (N == 0)      asm volatile("s_waitcnt vmcnt(0)" ::: "memory");
    else if constexpr (N == 2) asm volatile("s_waitcnt vmcnt(2)" ::: "memory");
    else if constexpr (N == 3) asm volatile("s_waitcnt vmcnt(3)" ::: "memory");
    else if constexpr (N == 4) asm volatile("s_waitcnt vmcnt(4)" ::: "memory");
    else static_assert(N == 0 || N == 2 || N == 3 || N == 4, "unsupported vmcnt");
}

struct GemmPtrs {
    const u16b* A[3];
    const u16b* B[3];
    const float* D[3];
    u16b* Cb[3];
    float* Cf[3];
    float scale[3];
    int vt[3];       // epilogue writes [B,H,64,S] (V-transposed)
    int hs[3];       // epilogue writes [B,H,S,64] (head-split)
};

// ---------- unified prep: z 0..2 inputs (convert), z 3..6 weights ----------
__global__ void prep_all(const float* __restrict__ q, const float* __restrict__ k,
                         const float* __restrict__ v,
                         const float* __restrict__ Wq, const float* __restrict__ Wk,
                         const float* __restrict__ Wv, const float* __restrict__ Wo,
                         u16b* __restrict__ oq, u16b* __restrict__ ok, u16b* __restrict__ ov,
                         u16b* __restrict__ wq, u16b* __restrict__ wk,
                         u16b* __restrict__ wv, u16b* __restrict__ wo,
                         u16b* __restrict__ wqt, u16b* __restrict__ wkt) {
    const int z = blockIdx.z;
    const int tid = threadIdx.x;
    if (z < 3) {
        const float* src = (z == 0) ? q : (z == 1) ? k : v;
        u16b* dst = (z == 0) ? oq : (z == 1) ? ok : ov;
        const int i = blockIdx.x * 256 + tid;
        float4 val = ((const float4*)src)[i];
        ushort4 o;
        o.x = f2b(val.x); o.y = f2b(val.y); o.z = f2b(val.z); o.w = f2b(val.w);
        ((ushort4*)dst)[i] = o;
        return;
    }
    if (blockIdx.x >= 1024) return;
    const int w = z - 3;
    const float* src = (w == 0) ? Wq : (w == 1) ? Wk : (w == 2) ? Wv : Wo;
    u16b* dst  = (w == 0) ? wq : (w == 1) ? wk : (w == 2) ? wv : wo;
    u16b* dstT = (w == 0) ? wqt : (w == 1) ? wkt : nullptr;
    __shared__ float t[32][33];
    const int bx = (blockIdx.x & 31) * 32, by = (blockIdx.x >> 5) * 32;
    const int x = tid & 31, y = tid >> 5;  // 32x8
#pragma unroll
    for (int r = 0; r < 4; ++r) {
        const int row = by + y + 8 * r;
        const float val = src[(size_t)row * EMBED + bx + x];
        dst[(size_t)row * EMBED + bx + x] = f2b(val);
        if (w < 2) t[y + 8 * r][x] = val;
    }
    if (w >= 2) return;
    __syncthreads();
#pragma unroll
    for (int r = 0; r < 4; ++r)
        dstT[(size_t)(bx + y + 8 * r) * EMBED + by + x] = f2b(t[x][y + 8 * r]);
}

// ---------- BM x BN bf16 MFMA NT GEMM, depth-2 prefetch + counted vmcnt ----------
// MODE 0: Cb = f2b(scale*AB)  (vt: [B,H,64,S] layout; hs: [B,H,S,64] layout)
// MODE 1: Cb = f2b(D - AB)
// MODE 2: Cf = AB (fp32)
template<int MODE, int BM, int BN>
__global__ __launch_bounds__(256) void gemm_big(GemmPtrs p, int M, int N, int K) {
    const int z = blockIdx.z;
    const u16b* __restrict__ A = p.A[z];
    const u16b* __restrict__ B = p.B[z];
    const float* __restrict__ D = p.D[z];
    u16b* __restrict__ Cb = p.Cb[z];
    float* __restrict__ Cf = p.Cf[z];
    const float scale = p.scale[z];
    const int vt = p.vt[z], hs = p.hs[z];

    constexpr int BK = 32;
    constexpr int IT = BM / 32;       // i-tiles per wave
    constexpr int JT = BN / 32;       // j-tiles per wave
    constexpr int IA = BM / 64;       // A staging issues per wave
    constexpr int IB = BN / 64;       // B staging issues per wave
    constexpr int LPW = IA + IB;      // per-wave loads per STAGE (vmcnt unit)
    __shared__ __align__(16) u16b As[2][BM * BK];
    __shared__ __align__(16) u16b Bs[2][BN * BK];

    const int tid = threadIdx.x;
    const int wave = tid >> 6, lane = tid & 63;
    const int quad = lane >> 4, l16 = lane & 15;
    const int wrow = wave >> 1, wcol = wave & 1;
    const int m0 = blockIdx.y * BM, n0 = blockIdx.x * BN;

    ffrag acc[IT][JT];
#pragma unroll
    for (int i = 0; i < IT; ++i)
#pragma unroll
        for (int j = 0; j < JT; ++j) acc[i][j] = ffrag{0.f, 0.f, 0.f, 0.f};

    const int srow = lane >> 2, schunk = lane & 3;

    // stage K-tile kt into buffer buf (LPW global_load_lds per wave)
    auto STAGE = [&](int buf, int kt) {
#pragma unroll
        for (int q = 0; q < IA; ++q) {
            int row = wave * (BM / 4) + q * 16;
            gload_lds16(A + (size_t)(m0 + row + srow) * K + kt + schunk * 8,
                        &As[buf][row * BK]);
        }
#pragma unroll
        for (int q = 0; q < IB; ++q) {
            int row = wave * (BN / 4) + q * 16;
            gload_lds16(B + (size_t)(n0 + row + srow) * K + kt + schunk * 8,
                        &Bs[buf][row * BK]);
        }
    };

    // prologue: tiles 0 and 1 in flight; wait only for tile 0
    STAGE(0, 0);
    STAGE(1, BK);
    wait_vmcnt<LPW>();
    __builtin_amdgcn_s_barrier();
    __builtin_amdgcn_sched_barrier(0);

    int cur = 0;
    for (int kt = 0; kt < K; kt += BK, cur ^= 1) {
        // 1) LDS -> regs for tile cur
        bfrag af[IT], bfv[JT];
#pragma unroll
        for (int i = 0; i < IT; ++i)
            af[i] = *(const bfrag*)&As[cur][(wrow * (BM / 2) + i * 16 + l16) * BK + quad * 8];
#pragma unroll
        for (int j = 0; j < JT; ++j)
            bfv[j] = *(const bfrag*)&Bs[cur][(wcol * (BN / 2) + j * 16 + l16) * BK + quad * 8];
        asm volatile("s_waitcnt lgkmcnt(0)" ::: "memory");
        __builtin_amdgcn_sched_barrier(0);
        __builtin_amdgcn_s_barrier();          // all waves done reading [cur]
        __builtin_amdgcn_sched_barrier(0);

        // 2) refill [cur] with tile t+2 (stays in flight across barriers)
        const bool stage = (kt + 2 * BK < K);
        if (stage) STAGE(cur, kt + 2 * BK);

        // 3) compute on regs — covers tile t+1's remaining latency
#pragma unroll
        for (int i = 0; i < IT; ++i)
#pragma unroll
            for (int j = 0; j < JT; ++j)
                acc[i][j] = __builtin_amdgcn_mfma_f32_16x16x32_bf16(af[i], bfv[j], acc[i][j], 0, 0, 0);

        // 4) tile t+1 (issued a full K-step ago) must be resident
        if (stage) wait_vmcnt<LPW>();
        else       wait_vmcnt<0>();
        __builtin_amdgcn_s_barrier();
        __builtin_amdgcn_sched_barrier(0);
    }

    if (MODE == 0 && vt) {
#pragma unroll
        for (int i = 0; i < IT; ++i)
#pragma unroll
            for (int j = 0; j < JT; ++j) {
                const int col = n0 + wcol * (BN / 2) + j * 16 + l16;
                const int h = col >> 6, d = col & 63;
                const int row0 = m0 + wrow * (BM / 2) + i * 16 + quad * 4;
                const int b = row0 >> 11, s = row0 & 2047;
                ushort4 o;
                o.x = f2b(acc[i][j][0]); o.y = f2b(acc[i][j][1]);
                o.z = f2b(acc[i][j][2]); o.w = f2b(acc[i][j][3]);
                *(ushort4*)&Cb[((size_t)(b * NHEADS + h) * HDIM + d) * SEQ + s] = o;
            }
        return;
    }
    if (MODE == 0 && hs) {
#pragma unroll
        for (int i = 0; i < IT; ++i)
#pragma unroll
        for (int j = 0; j < JT; ++j) {
                const int col = n0 + wcol * (BN / 2) + j * 16 + l16;
                const int h = col >> 6, d = col & 63;
                const int row0 = m0 + wrow * (BM / 2) + i * 16 + quad * 4;
                const int b = row0 >> 11, s0 = row0 & 2047;
#pragma unroll
                for (int r = 0; r < 4; ++r)
                    Cb[((size_t)(b * NHEADS + h) * SEQ + s0 + r) * HDIM + d] =
                        f2b(acc[i][j][r] * scale);
            }
        return;
    }

#pragma unroll
    for (int i = 0; i < IT; ++i)
#pragma unroll
        for (int j = 0; j < JT; ++j) {
            const int col = n0 + wcol * (BN / 2) + j * 16 + l16;
#pragma unroll
            for (int r = 0; r < 4; ++r) {
                const int row = m0 + wrow * (BM / 2) + i * 16 + quad * 4 + r;
                const size_t idx = (size_t)row * N + col;
                const float v = acc[i][j][r];
                if (MODE == 0) Cb[idx] = f2b(v * scale);
                else if (MODE == 1) Cb[idx] = f2b(D[idx] - v);
                else Cf[idx] = v;
            }
        }
}

// ---------- flash attention v6x: v6 + XCD-aware block swizzle ----------
// qp,kp: [B,H,S,64] bf16 (q pre-scaled); Vt: [B,H,64,S].
// 1D grid of 1024 blocks. The 16 q-tile blocks of one (h,b,split) group share
// the same 4 MB K/V half; default round-robin spreads them over all 8 XCDs
// (2 sharers per L2). Swizzle: xcd = n&7 selects the group's low 3 bits so all
// 16 sharers land on ONE XCD -> K/V staging loads become L2 hits.
// VERIFIED v6 core at 59.0 us (round 14). LDS staging is the coalescing layer:
// the no-LDS variant (v7, round 12) regressed to 131 us. setprio: null (r15).
__global__ __launch_bounds__(256) void flash_attn6(
    const u16b* __restrict__ Qp, const u16b* __restrict__ Kp,
    const u16b* __restrict__ Vt, float* __restrict__ Opart,
    float* __restrict__ Lpart)
{
    const int tid = threadIdx.x;
    const int wave = tid >> 6, lane = tid & 63;
    const int l32 = lane & 31, hi = lane >> 5;

    // bijective XCD swizzle: n -> (group g, q-tile qt), g's low 3 bits = n&7
    const int n = blockIdx.x;
    const int xcd = n & 7, t = n >> 3;
    const int qt = t & 15;
    const int g = ((t >> 4) << 3) | xcd;     // 0..63
    const int h = g >> 2;                     // 0..15
    const int b = (g >> 1) & 1, sp = g & 1;

    const int qb = qt * 128 + wave * 32;
    const int kt0 = sp * (SEQ / 2), kt1 = kt0 + SEQ / 2;

    __shared__ __align__(16) u16b Ks[2][64 * 64];    // [key][d], swizzled
    __shared__ __align__(16) u16b Vs[2][64 * 64];    // [d][key], swizzled

    const size_t hsbase = (size_t)(b * NHEADS + h) * SEQ;
    const size_t vtbase = (size_t)(b * NHEADS + h) * HDIM * SEQ;
    const size_t obase  = ((size_t)sp * MROWS + (size_t)b * SEQ) * EMBED + h * HDIM;

    // Q fragments: B-operand of 32x32x16 (col=q=l32, k = ks*16 + hi*8 + j)
    bfrag bq[4];
#pragma unroll
    for (int ks = 0; ks < 4; ++ks)
        bq[ks] = *(const bfrag*)&Qp[(hsbase + qb + l32) * HDIM + ks * 16 + hi * 8];

    f16frag ov0, ov1;   // O^T rows d=0..31 / 32..63, col q=l32
#pragma unroll
    for (int r = 0; r < 16; ++r) { ov0[r] = 0.f; ov1[r] = 0.f; }
    float l_run = 0.f;

    const int r0 = tid >> 3, c0 = tid & 7;
    const int sw0 = (r0 * 8 + (c0 ^ (r0 & 7))) * 8;
    const int sw1 = ((r0 + 32) * 8 + (c0 ^ (r0 & 7))) * 8;
    const u16b* kgb = Kp + hsbase * HDIM;
    const u16b* vgb = Vt + vtbase;

    // stage first tile -> buf 0
    {
        const u16b* kg = kgb + (size_t)kt0 * HDIM;
        bfrag k0 = *(const bfrag*)(kg + tid * 8);
        bfrag k1 = *(const bfrag*)(kg + (tid + 256) * 8);
        bfrag v0 = *(const bfrag*)(vgb + (size_t)r0 * SEQ + kt0 + c0 * 8);
        bfrag v1 = *(const bfrag*)(vgb + (size_t)(r0 + 32) * SEQ + kt0 + c0 * 8);
        *(bfrag*)&Ks[0][sw0] = k0;  *(bfrag*)&Ks[0][sw1] = k1;
        *(bfrag*)&Vs[0][sw0] = v0;  *(bfrag*)&Vs[0][sw1] = v1;
    }
    __syncthreads();

    int p = 0;
    for (int kt = kt0; kt < kt1; kt += 64, p ^= 1) {
        const bool more = (kt + 64) < kt1;
        bfrag kn0, kn1, vn0, vn1;
        if (more) {
            const u16b* kg = kgb + (size_t)(kt + 64) * HDIM;
            kn0 = *(const bfrag*)(kg + tid * 8);
            kn1 = *(const bfrag*)(kg + (tid + 256) * 8);
            vn0 = *(const bfrag*)(vgb + (size_t)r0 * SEQ + kt + 64 + c0 * 8);
            vn1 = *(const bfrag*)(vgb + (size_t)(r0 + 32) * SEQ + kt + 64 + c0 * 8);
        }

        // --- S^T = K Q^T : two 32x32 tiles (keys 0-31, 32-63) ---
        f16frag St0, St1;
#pragma unroll
        for (int r = 0; r < 16; ++r) { St0[r] = 0.f; St1[r] = 0.f; }
#pragma unroll
        for (int ks = 0; ks < 4; ++ks) {
            const int ch = ks * 2 + hi;
            bfrag k0 = *(const bfrag*)&Ks[p][(l32 * 8 + (ch ^ (l32 & 7))) * 8];
            bfrag k1 = *(const bfrag*)&Ks[p][((32 + l32) * 8 + (ch ^ (l32 & 7))) * 8];
            St0 = __builtin_amdgcn_mfma_f32_32x32x16_bf16(k0, bq[ks], St0, 0, 0, 0);
            St1 = __builtin_amdgcn_mfma_f32_32x32x16_bf16(k1, bq[ks], St1, 0, 0, 0);
        }

        // --- max-free softmax: exp2 all, column sum for q=l32 ---
        float rs = 0.f;
#pragma unroll
        for (int r = 0; r < 16; ++r) {
            const float a = __builtin_amdgcn_exp2f(St0[r]);
            const float c = __builtin_amdgcn_exp2f(St1[r]);
            St0[r] = a; St1[r] = c;
            rs += a + c;
        }
        rs += __shfl_xor(rs, 32);
        l_run += rs;

        // --- P -> bf16 B-operands fully in-register ---
        unsigned d0[8], d1[8];
#pragma unroll
        for (int rr = 0; rr < 8; ++rr) {
            d0[rr] = cvtpk_bf16(St0[2 * rr], St0[2 * rr + 1]);
            d1[rr] = cvtpk_bf16(St1[2 * rr], St1[2 * rr + 1]);
        }
        bfrag bp[4];
        {
            int a0, a1, b0, b1, c0w, c1, e0, e1;
            plane_swap(d0[0], d0[2], a0, a1);
            plane_swap(d0[1], d0[3], b0, b1);
            i32x4 w = { a0, b0, a1, b1 };
            bp[0] = __builtin_bit_cast(bfrag, w);
            plane_swap(d0[4], d0[6], c0w, c1);
            plane_swap(d0[5], d0[7], e0, e1);
            i32x4 w2 = { c0w, e0, c1, e1 };
            bp[1] = __builtin_bit_cast(bfrag, w2);
        }
        {
            int a0, a1, b0, b1, c0w, c1, e0, e1;
            plane_swap(d1[0], d1[2], a0, a1);
            plane_swap(d1[1], d1[3], b0, b1);
            i32x4 w = { a0, b0, a1, b1 };
            bp[2] = __builtin_bit_cast(bfrag, w);
            plane_swap(d1[4], d1[6], c0w, c1);
            plane_swap(d1[5], d1[7], e0, e1);
            i32x4 w2 = { c0w, e0, c1, e1 };
            bp[3] = __builtin_bit_cast(bfrag, w2);
        }

        // --- O^T += V^T P : two 32x32 d-tiles x 4 key-steps of 16 ---
#pragma unroll
        for (int ks = 0; ks < 4; ++ks) {
            const int ch = ks * 2 + hi;
            bfrag v0 = *(const bfrag*)&Vs[p][(l32 * 8 + (ch ^ (l32 & 7))) * 8];
            bfrag v1 = *(const bfrag*)&Vs[p][((32 + l32) * 8 + (ch ^ (l32 & 7))) * 8];
            ov0 = __builtin_amdgcn_mfma_f32_32x32x16_bf16(v0, bp[ks], ov0, 0, 0, 0);
            ov1 = __builtin_amdgcn_mfma_f32_32x32x16_bf16(v1, bp[ks], ov1, 0, 0, 0);
        }

        if (more) {
            *(bfrag*)&Ks[p ^ 1][sw0] = kn0;  *(bfrag*)&Ks[p ^ 1][sw1] = kn1;
            *(bfrag*)&Vs[p ^ 1][sw0] = vn0;  *(bfrag*)&Vs[p ^ 1][sw1] = vn1;
            __syncthreads();
        }
    }

    // epilogue: raw partial O (fp32) + partial l
    const size_t orow = obase + (size_t)(qb + l32) * EMBED;
#pragma unroll
    for (int rr = 0; rr < 4; ++rr) {
        float4 o0, o1;
        o0.x = ov0[4 * rr + 0]; o0.y = ov0[4 * rr + 1];
        o0.z = ov0[4 * rr + 2]; o0.w = ov0[4 * rr + 3];
        o1.x = ov1[4 * rr + 0]; o1.y = ov1[4 * rr + 1];
        o1.z = ov1[4 * rr + 2]; o1.w = ov1[4 * rr + 3];
        *(float4*)&Opart[orow + rr * 8 + hi * 4] = o0;
        *(float4*)&Opart[orow + 32 + rr * 8 + hi * 4] = o1;
    }
    if (hi == 0)
        Lpart[((size_t)sp * BATCH * NHEADS + b * NHEADS + h) * SEQ + qb + l32] = l_run;
}

// ---------- combine split-K partials -> ao bf16 [B,S,E] ----------
__global__ void combine_o(const float* __restrict__ O0, const float* __restrict__ O1,
                          const float* __restrict__ L0, const float* __restrict__ L1,
                          u16b* __restrict__ ao) {
    const int i = blockIdx.x * 256 + threadIdx.x;   // float4 index (1M total)
    const int e0 = i << 2;
    const int row = e0 >> 10, col = e0 & 1023;
    const int lidx = ((row >> 11) * NHEADS + (col >> 6)) * SEQ + (row & 2047);
    float4 a = ((const float4*)O0)[i];
    float4 c = ((const float4*)O1)[i];
    const float inv = 1.f / (L0[lidx] + L1[lidx]);
    ushort4 o;
    o.x = f2b((a.x + c.x) * inv); o.y = f2b((a.y + c.y) * inv);
    o.z = f2b((a.z + c.z) * inv); o.w = f2b((a.w + c.w) * inv);
    ((ushort4*)ao)[i] = o;
}

// ---------- launch ----------
extern "C" void kernel_launch(void* const* d_in, const int* in_sizes, int n_in,
                              void* d_out, int out_size, void* d_ws, size_t ws_size,
                              hipStream_t stream) {
    const float* query = (const float*)d_in[0];
    const float* key_  = (const float*)d_in[1];
    const float* value = (const float*)d_in[2];
    const float* Wq    = (const float*)d_in[3];
    const float* Wk    = (const float*)d_in[4];
    const float* Wv    = (const float*)d_in[5];
    const float* Wo    = (const float*)d_in[6];
    float* out = (float*)d_out;

    char* ws = (char*)d_ws;
    const size_t MB = 1024 * 1024;
    u16b* xq  = (u16b*)(ws + 0 * MB);    // 8 MB, dead after proj
    u16b* xk  = (u16b*)(ws + 8 * MB);    // dead after proj
    u16b* xv  = (u16b*)(ws + 16 * MB);   // dead after proj
    u16b* wq  = (u16b*)(ws + 24 * MB);   // dead after orth
    u16b* wk  = (u16b*)(ws + 26 * MB);   // dead after orth
    u16b* wv  = (u16b*)(ws + 28 * MB);   // dead after proj
    u16b* gq  = (u16b*)(ws + 32 * MB);   // dead after orth
    u16b* gk  = (u16b*)(ws + 34 * MB);   // dead after orth
    u16b* wqo = (u16b*)(ws + 36 * MB);   // dead after proj
    u16b* wko = (u16b*)(ws + 38 * MB);   // dead after proj
    u16b* wo  = (u16b*)(ws + 40 * MB);   // live until out-proj
    u16b* qp  = (u16b*)(ws + 44 * MB);   // [B,H,S,64], dead after attn
    u16b* kp  = (u16b*)(ws + 52 * MB);   // dead after attn
    u16b* Vt  = (u16b*)(ws + 60 * MB);   // [B,H,64,S], dead after attn
    u16b* wqt = (u16b*)(ws + 60 * MB);   // inside Vt region: dead after gram, Vt written later
    u16b* wkt = (u16b*)(ws + 62 * MB);
    float* Op  = (float*)(ws + 0 * MB);  // 2 x 16 MB fp32 [split][B,S,E] @ 0..32
    float* Lp  = (float*)(ws + 32 * MB); // 2 x 256 KB [split][B,H,S]
    u16b*  ao  = (u16b*)(ws + 44 * MB);  // combine output over dead qp

    // 1) unified prep (inputs + weights)
    prep_all<<<dim3(MROWS * EMBED / 1024, 1, 7), dim3(256), 0, stream>>>(
        query, key_, value, Wq, Wk, Wv, Wo,
        xq, xk, xv, wq, wk, wv, wo, wqt, wkt);

    // 2) Grams (z-batched): gq = Wq^T Wq, gk = Wk^T Wk  (64x64 tiles, 512 blocks)
    {
        GemmPtrs p{};
        p.A[0] = wqt; p.B[0] = wqt; p.Cb[0] = gq; p.scale[0] = 1.f;
        p.A[1] = wkt; p.B[1] = wkt; p.Cb[1] = gk; p.scale[1] = 1.f;
        gemm_big<0, 64, 64><<<dim3(EMBED / 64, EMBED / 64, 2), dim3(256), 0, stream>>>(
            p, EMBED, EMBED, EMBED);
    }
    // 3) Orth (z-batched): wqo = Wq - Wq*gk, wko = Wk - Wk*gq
    {
        GemmPtrs p{};
        p.A[0] = wq; p.B[0] = gk; p.D[0] = Wq; p.Cb[0] = wqo;
        p.A[1] = wk; p.B[1] = gq; p.D[1] = Wk; p.Cb[1] = wko;
        gemm_big<1, 64, 64><<<dim3(EMBED / 64, EMBED / 64, 2), dim3(256), 0, stream>>>(
            p, EMBED, EMBED, EMBED);
    }
    // 4) Projections (z-batched): q,k head-split; V transposed
    {
        GemmPtrs p{};
        p.A[0] = xq; p.B[0] = wqo; p.Cb[0] = qp; p.scale[0] = SCALE_Q; p.hs[0] = 1;
        p.A[1] = xk; p.B[1] = wko; p.Cb[1] = kp; p.scale[1] = 1.f;     p.hs[1] = 1;
        p.A[2] = xv; p.B[2] = wv;  p.Cb[2] = Vt; p.scale[2] = 1.f;     p.vt[2] = 1;
        gemm_big<0, 128, 128><<<dim3(EMBED / 128, MROWS / 128, 3), dim3(256), 0, stream>>>(
            p, MROWS, EMBED, EMBED);
    }
    // 5) Attention, split-K=2 (1024 blocks, 1D XCD-swizzled grid)
    flash_attn6<<<dim3(SEQ / 128 * NHEADS * BATCH * 2, 1, 1), dim3(256), 0, stream>>>(
        qp, kp, Vt, Op, Lp);
    // 6) Combine partials -> ao
    combine_o<<<dim3(MROWS * EMBED / 1024), dim3(256), 0, stream>>>(
        Op, Op + (size_t)MROWS * EMBED, Lp, Lp + (size_t)BATCH * NHEADS * SEQ, ao);
    // 7) Output projection (fp32 out), BM=64 for 512-block occupancy
    {
        GemmPtrs p{};
        p.A[0] = ao; p.B[0] = wo; p.Cf[0] = out; p.scale[0] = 1.f;
        gemm_big<2, 64, 128><<<dim3(EMBED / 128, MROWS / 64, 1), dim3(256), 0, stream>>>(
            p, MROWS, EMBED, EMBED);
    }
}

// Round 17
// 259.482 us; speedup vs baseline: 1.0564x; 1.0507x over previous
//
#include <hip/hip_runtime.h>
#include <math.h>

constexpr int EMBED  = 1024;
constexpr int NHEADS = 16;
constexpr int HDIM   = 64;
constexpr int BATCH  = 2;
constexpr int SEQ    = 2048;
constexpr int MROWS  = BATCH * SEQ;  // 4096

typedef unsigned short u16b;  // bf16 storage
typedef __attribute__((ext_vector_type(8))) short bfrag;   // 8 bf16 (4 VGPRs)
typedef __attribute__((ext_vector_type(4))) float ffrag;   // 4 fp32 acc
typedef __attribute__((ext_vector_type(16))) float f16frag; // 16 fp32 acc (32x32)
typedef __attribute__((ext_vector_type(4))) int i32x4;

// softmax scale folded with log2(e): exp(0.125*x) == exp2(0.18033688*x)
#define SCALE_Q 0.18033688f

__device__ __forceinline__ u16b f2b(float f) {          // RNE
    union { float f; unsigned u; } v; v.f = f;
    unsigned r = v.u + 0x7fffu + ((v.u >> 16) & 1u);
    return (u16b)(r >> 16);
}

__device__ __forceinline__ unsigned cvtpk_bf16(float a, float b) {
    unsigned r;
    asm("v_cvt_pk_bf16_f32 %0, %1, %2" : "=v"(r) : "v"(a), "v"(b));
    return r;
}

// permlane32_swap wrapper: returns {this_lane_word, swapped_word} as ints
__device__ __forceinline__ void plane_swap(unsigned a, unsigned b, int& lo, int& hi) {
    auto r = __builtin_amdgcn_permlane32_swap((int)a, (int)b, false, false);
    lo = (int)r[0];
    hi = (int)r[1];
}

__device__ __forceinline__ void gload_lds16(const u16b* g, u16b* l) {
    __builtin_amdgcn_global_load_lds(
        (const __attribute__((address_space(1))) void*)g,
        (__attribute__((address_space(3))) void*)l,
        16, 0, 0);
}

template<int N>
__device__ __forceinline__ void wait_vmcnt() {
    if constexpr (N == 0)      asm volatile("s_waitcnt vmcnt(0)" ::: "memory");
    else if constexpr (N == 2) asm volatile("s_waitcnt vmcnt(2)" ::: "memory");
    else if constexpr (N == 3) asm volatile("s_waitcnt vmcnt(3)" ::: "memory");
    else if constexpr (N == 4) asm volatile("s_waitcnt vmcnt(4)" ::: "memory");
    else static_assert(N == 0 || N == 2 || N == 3 || N == 4, "unsupported vmcnt");
}

struct GemmPtrs {
    const u16b* A[3];
    const u16b* B[3];
    const float* D[3];
    u16b* Cb[3];
    float* Cf[3];
    float scale[3];
    int vt[3];       // epilogue writes [B,H,64,S] (V-transposed)
    int hs[3];       // epilogue writes [B,H,S,64] (head-split)
};

// ---------- unified prep: z 0..2 inputs (convert), z 3..6 weights ----------
__global__ void prep_all(const float* __restrict__ q, const float* __restrict__ k,
                         const float* __restrict__ v,
                         const float* __restrict__ Wq, const float* __restrict__ Wk,
                         const float* __restrict__ Wv, const float* __restrict__ Wo,
                         u16b* __restrict__ oq, u16b* __restrict__ ok, u16b* __restrict__ ov,
                         u16b* __restrict__ wq, u16b* __restrict__ wk,
                         u16b* __restrict__ wv, u16b* __restrict__ wo,
                         u16b* __restrict__ wqt, u16b* __restrict__ wkt) {
    const int z = blockIdx.z;
    const int tid = threadIdx.x;
    if (z < 3) {
        const float* src = (z == 0) ? q : (z == 1) ? k : v;
        u16b* dst = (z == 0) ? oq : (z == 1) ? ok : ov;
        const int i = blockIdx.x * 256 + tid;
        float4 val = ((const float4*)src)[i];
        ushort4 o;
        o.x = f2b(val.x); o.y = f2b(val.y); o.z = f2b(val.z); o.w = f2b(val.w);
        ((ushort4*)dst)[i] = o;
        return;
    }
    if (blockIdx.x >= 1024) return;
    const int w = z - 3;
    const float* src = (w == 0) ? Wq : (w == 1) ? Wk : (w == 2) ? Wv : Wo;
    u16b* dst  = (w == 0) ? wq : (w == 1) ? wk : (w == 2) ? wv : wo;
    u16b* dstT = (w == 0) ? wqt : (w == 1) ? wkt : nullptr;
    __shared__ float t[32][33];
    const int bx = (blockIdx.x & 31) * 32, by = (blockIdx.x >> 5) * 32;
    const int x = tid & 31, y = tid >> 5;  // 32x8
#pragma unroll
    for (int r = 0; r < 4; ++r) {
        const int row = by + y + 8 * r;
        const float val = src[(size_t)row * EMBED + bx + x];
        dst[(size_t)row * EMBED + bx + x] = f2b(val);
        if (w < 2) t[y + 8 * r][x] = val;
    }
    if (w >= 2) return;
    __syncthreads();
#pragma unroll
    for (int r = 0; r < 4; ++r)
        dstT[(size_t)(bx + y + 8 * r) * EMBED + by + x] = f2b(t[x][y + 8 * r]);
}

// ---------- BM x BN bf16 MFMA NT GEMM, depth-2 prefetch + counted vmcnt ----------
// MODE 0: Cb = f2b(scale*AB)  (vt: [B,H,64,S] layout; hs: [B,H,S,64] layout)
// MODE 1: Cb = f2b(D - AB)
// MODE 2: Cf = AB (fp32)
template<int MODE, int BM, int BN>
__global__ __launch_bounds__(256) void gemm_big(GemmPtrs p, int M, int N, int K) {
    const int z = blockIdx.z;
    const u16b* __restrict__ A = p.A[z];
    const u16b* __restrict__ B = p.B[z];
    const float* __restrict__ D = p.D[z];
    u16b* __restrict__ Cb = p.Cb[z];
    float* __restrict__ Cf = p.Cf[z];
    const float scale = p.scale[z];
    const int vt = p.vt[z], hs = p.hs[z];

    constexpr int BK = 32;
    constexpr int IT = BM / 32;       // i-tiles per wave
    constexpr int JT = BN / 32;       // j-tiles per wave
    constexpr int IA = BM / 64;       // A staging issues per wave
    constexpr int IB = BN / 64;       // B staging issues per wave
    constexpr int LPW = IA + IB;      // per-wave loads per STAGE (vmcnt unit)
    __shared__ __align__(16) u16b As[2][BM * BK];
    __shared__ __align__(16) u16b Bs[2][BN * BK];

    const int tid = threadIdx.x;
    const int wave = tid >> 6, lane = tid & 63;
    const int quad = lane >> 4, l16 = lane & 15;
    const int wrow = wave >> 1, wcol = wave & 1;
    const int m0 = blockIdx.y * BM, n0 = blockIdx.x * BN;

    ffrag acc[IT][JT];
#pragma unroll
    for (int i = 0; i < IT; ++i)
#pragma unroll
        for (int j = 0; j < JT; ++j) acc[i][j] = ffrag{0.f, 0.f, 0.f, 0.f};

    const int srow = lane >> 2, schunk = lane & 3;

    // stage K-tile kt into buffer buf (LPW global_load_lds per wave)
    auto STAGE = [&](int buf, int kt) {
#pragma unroll
        for (int q = 0; q < IA; ++q) {
            int row = wave * (BM / 4) + q * 16;
            gload_lds16(A + (size_t)(m0 + row + srow) * K + kt + schunk * 8,
                        &As[buf][row * BK]);
        }
#pragma unroll
        for (int q = 0; q < IB; ++q) {
            int row = wave * (BN / 4) + q * 16;
            gload_lds16(B + (size_t)(n0 + row + srow) * K + kt + schunk * 8,
                        &Bs[buf][row * BK]);
        }
    };

    // prologue: tiles 0 and 1 in flight; wait only for tile 0
    STAGE(0, 0);
    STAGE(1, BK);
    wait_vmcnt<LPW>();
    __builtin_amdgcn_s_barrier();
    __builtin_amdgcn_sched_barrier(0);

    int cur = 0;
    for (int kt = 0; kt < K; kt += BK, cur ^= 1) {
        // 1) LDS -> regs for tile cur
        bfrag af[IT], bfv[JT];
#pragma unroll
        for (int i = 0; i < IT; ++i)
            af[i] = *(const bfrag*)&As[cur][(wrow * (BM / 2) + i * 16 + l16) * BK + quad * 8];
#pragma unroll
        for (int j = 0; j < JT; ++j)
            bfv[j] = *(const bfrag*)&Bs[cur][(wcol * (BN / 2) + j * 16 + l16) * BK + quad * 8];
        asm volatile("s_waitcnt lgkmcnt(0)" ::: "memory");
        __builtin_amdgcn_sched_barrier(0);
        __builtin_amdgcn_s_barrier();          // all waves done reading [cur]
        __builtin_amdgcn_sched_barrier(0);

        // 2) refill [cur] with tile t+2 (stays in flight across barriers)
        const bool stage = (kt + 2 * BK < K);
        if (stage) STAGE(cur, kt + 2 * BK);

        // 3) compute on regs — covers tile t+1's remaining latency
#pragma unroll
        for (int i = 0; i < IT; ++i)
#pragma unroll
            for (int j = 0; j < JT; ++j)
                acc[i][j] = __builtin_amdgcn_mfma_f32_16x16x32_bf16(af[i], bfv[j], acc[i][j], 0, 0, 0);

        // 4) tile t+1 (issued a full K-step ago) must be resident
        if (stage) wait_vmcnt<LPW>();
        else       wait_vmcnt<0>();
        __builtin_amdgcn_s_barrier();
        __builtin_amdgcn_sched_barrier(0);
    }

    if (MODE == 0 && vt) {
#pragma unroll
        for (int i = 0; i < IT; ++i)
#pragma unroll
            for (int j = 0; j < JT; ++j) {
                const int col = n0 + wcol * (BN / 2) + j * 16 + l16;
                const int h = col >> 6, d = col & 63;
                const int row0 = m0 + wrow * (BM / 2) + i * 16 + quad * 4;
                const int b = row0 >> 11, s = row0 & 2047;
                ushort4 o;
                o.x = f2b(acc[i][j][0]); o.y = f2b(acc[i][j][1]);
                o.z = f2b(acc[i][j][2]); o.w = f2b(acc[i][j][3]);
                *(ushort4*)&Cb[((size_t)(b * NHEADS + h) * HDIM + d) * SEQ + s] = o;
            }
        return;
    }
    if (MODE == 0 && hs) {
#pragma unroll
        for (int i = 0; i < IT; ++i)
#pragma unroll
        for (int j = 0; j < JT; ++j) {
                const int col = n0 + wcol * (BN / 2) + j * 16 + l16;
                const int h = col >> 6, d = col & 63;
                const int row0 = m0 + wrow * (BM / 2) + i * 16 + quad * 4;
                const int b = row0 >> 11, s0 = row0 & 2047;
#pragma unroll
                for (int r = 0; r < 4; ++r)
                    Cb[((size_t)(b * NHEADS + h) * SEQ + s0 + r) * HDIM + d] =
                        f2b(acc[i][j][r] * scale);
            }
        return;
    }

#pragma unroll
    for (int i = 0; i < IT; ++i)
#pragma unroll
        for (int j = 0; j < JT; ++j) {
            const int col = n0 + wcol * (BN / 2) + j * 16 + l16;
#pragma unroll
            for (int r = 0; r < 4; ++r) {
                const int row = m0 + wrow * (BM / 2) + i * 16 + quad * 4 + r;
                const size_t idx = (size_t)row * N + col;
                const float v = acc[i][j][r];
                if (MODE == 0) Cb[idx] = f2b(v * scale);
                else if (MODE == 1) Cb[idx] = f2b(D[idx] - v);
                else Cf[idx] = v;
            }
        }
}

// ---------- flash attention v8: no split-K, direct bf16 output ----------
// qp,kp: [B,H,S,64] bf16 (q pre-scaled); Vt: [B,H,64,S]. ao: [B,S,E] bf16.
// 512 blocks (32 (b,h)-groups x 16 q-tiles), each walks all 2048 keys.
// Max-free softmax => final O = O_acc / l, applied in epilogue (exact).
// XCD swizzle: group's low 3 bits = n&7 so a group's 16 q-tile sharers land
// on one XCD (L2 reuse; r16: FETCH 71.7->16.4 MB).
// VERIFIED v6 core at 59.0/57.4 us. LDS staging is the coalescing layer (v7
// no-LDS regressed to 131 us). setprio: null (r15).
__global__ __launch_bounds__(256) void flash_attn8(
    const u16b* __restrict__ Qp, const u16b* __restrict__ Kp,
    const u16b* __restrict__ Vt, u16b* __restrict__ ao)
{
    const int tid = threadIdx.x;
    const int wave = tid >> 6, lane = tid & 63;
    const int l32 = lane & 31, hi = lane >> 5;

    // bijective XCD swizzle: n -> (group g, q-tile qt), g's low 3 bits = n&7
    const int n = blockIdx.x;          // 0..511
    const int xcd = n & 7, t = n >> 3; // t: 0..63
    const int qt = t & 15;
    const int g = ((t >> 4) << 3) | xcd;   // 0..31
    const int b = g >> 4;                   // 0..1
    const int h = g & 15;                   // 0..15

    const int qb = qt * 128 + wave * 32;

    __shared__ __align__(16) u16b Ks[2][64 * 64];    // [key][d], swizzled
    __shared__ __align__(16) u16b Vs[2][64 * 64];    // [d][key], swizzled

    const size_t hsbase = (size_t)(b * NHEADS + h) * SEQ;
    const size_t vtbase = (size_t)(b * NHEADS + h) * HDIM * SEQ;

    // Q fragments: B-operand of 32x32x16 (col=q=l32, k = ks*16 + hi*8 + j)
    bfrag bq[4];
#pragma unroll
    for (int ks = 0; ks < 4; ++ks)
        bq[ks] = *(const bfrag*)&Qp[(hsbase + qb + l32) * HDIM + ks * 16 + hi * 8];

    f16frag ov0, ov1;   // O^T rows d=0..31 / 32..63, col q=l32
#pragma unroll
    for (int r = 0; r < 16; ++r) { ov0[r] = 0.f; ov1[r] = 0.f; }
    float l_run = 0.f;

    const int r0 = tid >> 3, c0 = tid & 7;
    const int sw0 = (r0 * 8 + (c0 ^ (r0 & 7))) * 8;
    const int sw1 = ((r0 + 32) * 8 + (c0 ^ (r0 & 7))) * 8;
    const u16b* kgb = Kp + hsbase * HDIM;
    const u16b* vgb = Vt + vtbase;

    // stage first tile -> buf 0
    {
        bfrag k0 = *(const bfrag*)(kgb + tid * 8);
        bfrag k1 = *(const bfrag*)(kgb + (tid + 256) * 8);
        bfrag v0 = *(const bfrag*)(vgb + (size_t)r0 * SEQ + c0 * 8);
        bfrag v1 = *(const bfrag*)(vgb + (size_t)(r0 + 32) * SEQ + c0 * 8);
        *(bfrag*)&Ks[0][sw0] = k0;  *(bfrag*)&Ks[0][sw1] = k1;
        *(bfrag*)&Vs[0][sw0] = v0;  *(bfrag*)&Vs[0][sw1] = v1;
    }
    __syncthreads();

    int p = 0;
    for (int kt = 0; kt < SEQ; kt += 64, p ^= 1) {
        const bool more = (kt + 64) < SEQ;
        bfrag kn0, kn1, vn0, vn1;
        if (more) {
            const u16b* kg = kgb + (size_t)(kt + 64) * HDIM;
            kn0 = *(const bfrag*)(kg + tid * 8);
            kn1 = *(const bfrag*)(kg + (tid + 256) * 8);
            vn0 = *(const bfrag*)(vgb + (size_t)r0 * SEQ + kt + 64 + c0 * 8);
            vn1 = *(const bfrag*)(vgb + (size_t)(r0 + 32) * SEQ + kt + 64 + c0 * 8);
        }

        // --- S^T = K Q^T : two 32x32 tiles (keys 0-31, 32-63) ---
        f16frag St0, St1;
#pragma unroll
        for (int r = 0; r < 16; ++r) { St0[r] = 0.f; St1[r] = 0.f; }
#pragma unroll
        for (int ks = 0; ks < 4; ++ks) {
            const int ch = ks * 2 + hi;
            bfrag k0 = *(const bfrag*)&Ks[p][(l32 * 8 + (ch ^ (l32 & 7))) * 8];
            bfrag k1 = *(const bfrag*)&Ks[p][((32 + l32) * 8 + (ch ^ (l32 & 7))) * 8];
            St0 = __builtin_amdgcn_mfma_f32_32x32x16_bf16(k0, bq[ks], St0, 0, 0, 0);
            St1 = __builtin_amdgcn_mfma_f32_32x32x16_bf16(k1, bq[ks], St1, 0, 0, 0);
        }

        // --- max-free softmax: exp2 all, column sum for q=l32 ---
        float rs = 0.f;
#pragma unroll
        for (int r = 0; r < 16; ++r) {
            const float a = __builtin_amdgcn_exp2f(St0[r]);
            const float c = __builtin_amdgcn_exp2f(St1[r]);
            St0[r] = a; St1[r] = c;
            rs += a + c;
        }
        rs += __shfl_xor(rs, 32);
        l_run += rs;

        // --- P -> bf16 B-operands fully in-register ---
        unsigned d0[8], d1[8];
#pragma unroll
        for (int rr = 0; rr < 8; ++rr) {
            d0[rr] = cvtpk_bf16(St0[2 * rr], St0[2 * rr + 1]);
            d1[rr] = cvtpk_bf16(St1[2 * rr], St1[2 * rr + 1]);
        }
        bfrag bp[4];
        {
            int a0, a1, b0, b1, c0w, c1, e0, e1;
            plane_swap(d0[0], d0[2], a0, a1);
            plane_swap(d0[1], d0[3], b0, b1);
            i32x4 w = { a0, b0, a1, b1 };
            bp[0] = __builtin_bit_cast(bfrag, w);
            plane_swap(d0[4], d0[6], c0w, c1);
            plane_swap(d0[5], d0[7], e0, e1);
            i32x4 w2 = { c0w, e0, c1, e1 };
            bp[1] = __builtin_bit_cast(bfrag, w2);
        }
        {
            int a0, a1, b0, b1, c0w, c1, e0, e1;
            plane_swap(d1[0], d1[2], a0, a1);
            plane_swap(d1[1], d1[3], b0, b1);
            i32x4 w = { a0, b0, a1, b1 };
            bp[2] = __builtin_bit_cast(bfrag, w);
            plane_swap(d1[4], d1[6], c0w, c1);
            plane_swap(d1[5], d1[7], e0, e1);
            i32x4 w2 = { c0w, e0, c1, e1 };
            bp[3] = __builtin_bit_cast(bfrag, w2);
        }

        // --- O^T += V^T P : two 32x32 d-tiles x 4 key-steps of 16 ---
#pragma unroll
        for (int ks = 0; ks < 4; ++ks) {
            const int ch = ks * 2 + hi;
            bfrag v0 = *(const bfrag*)&Vs[p][(l32 * 8 + (ch ^ (l32 & 7))) * 8];
            bfrag v1 = *(const bfrag*)&Vs[p][((32 + l32) * 8 + (ch ^ (l32 & 7))) * 8];
            ov0 = __builtin_amdgcn_mfma_f32_32x32x16_bf16(v0, bp[ks], ov0, 0, 0, 0);
            ov1 = __builtin_amdgcn_mfma_f32_32x32x16_bf16(v1, bp[ks], ov1, 0, 0, 0);
        }

        if (more) {
            *(bfrag*)&Ks[p ^ 1][sw0] = kn0;  *(bfrag*)&Ks[p ^ 1][sw1] = kn1;
            *(bfrag*)&Vs[p ^ 1][sw0] = vn0;  *(bfrag*)&Vs[p ^ 1][sw1] = vn1;
            __syncthreads();
        }
    }

    // epilogue: O = O_acc / l, written directly as bf16 [B,S,E]
    // ov reg r -> d = (r&3) + 8*(r>>2) + 4*hi (+32 for ov1), q = l32
    const float inv = 1.f / l_run;
    const size_t orow = ((size_t)b * SEQ + qb + l32) * EMBED + h * HDIM;
#pragma unroll
    for (int rr = 0; rr < 4; ++rr) {
        ushort4 o0, o1;
        o0.x = f2b(ov0[4 * rr + 0] * inv); o0.y = f2b(ov0[4 * rr + 1] * inv);
        o0.z = f2b(ov0[4 * rr + 2] * inv); o0.w = f2b(ov0[4 * rr + 3] * inv);
        o1.x = f2b(ov1[4 * rr + 0] * inv); o1.y = f2b(ov1[4 * rr + 1] * inv);
        o1.z = f2b(ov1[4 * rr + 2] * inv); o1.w = f2b(ov1[4 * rr + 3] * inv);
        *(ushort4*)&ao[orow + rr * 8 + hi * 4] = o0;
        *(ushort4*)&ao[orow + 32 + rr * 8 + hi * 4] = o1;
    }
}

// ---------- launch ----------
extern "C" void kernel_launch(void* const* d_in, const int* in_sizes, int n_in,
                              void* d_out, int out_size, void* d_ws, size_t ws_size,
                              hipStream_t stream) {
    const float* query = (const float*)d_in[0];
    const float* key_  = (const float*)d_in[1];
    const float* value = (const float*)d_in[2];
    const float* Wq    = (const float*)d_in[3];
    const float* Wk    = (const float*)d_in[4];
    const float* Wv    = (const float*)d_in[5];
    const float* Wo    = (const float*)d_in[6];
    float* out = (float*)d_out;

    char* ws = (char*)d_ws;
    const size_t MB = 1024 * 1024;
    u16b* xq  = (u16b*)(ws + 0 * MB);    // 8 MB, dead after proj
    u16b* xk  = (u16b*)(ws + 8 * MB);    // dead after proj
    u16b* xv  = (u16b*)(ws + 16 * MB);   // dead after proj
    u16b* wq  = (u16b*)(ws + 24 * MB);   // dead after orth
    u16b* wk  = (u16b*)(ws + 26 * MB);   // dead after orth
    u16b* wv  = (u16b*)(ws + 28 * MB);   // dead after proj
    u16b* gq  = (u16b*)(ws + 32 * MB);   // dead after orth
    u16b* gk  = (u16b*)(ws + 34 * MB);   // dead after orth
    u16b* wqo = (u16b*)(ws + 36 * MB);   // dead after proj
    u16b* wko = (u16b*)(ws + 38 * MB);   // dead after proj
    u16b* wo  = (u16b*)(ws + 40 * MB);   // live until out-proj
    u16b* qp  = (u16b*)(ws + 44 * MB);   // [B,H,S,64], dead after attn
    u16b* kp  = (u16b*)(ws + 52 * MB);   // dead after attn
    u16b* Vt  = (u16b*)(ws + 60 * MB);   // [B,H,64,S], dead after attn
    u16b* wqt = (u16b*)(ws + 60 * MB);   // inside Vt region: dead after gram, Vt written later
    u16b* wkt = (u16b*)(ws + 62 * MB);
    u16b* ao  = (u16b*)(ws + 0 * MB);    // attn output [B,S,E] bf16 over dead xq

    // 1) unified prep (inputs + weights)
    prep_all<<<dim3(MROWS * EMBED / 1024, 1, 7), dim3(256), 0, stream>>>(
        query, key_, value, Wq, Wk, Wv, Wo,
        xq, xk, xv, wq, wk, wv, wo, wqt, wkt);

    // 2) Grams (z-batched): gq = Wq^T Wq, gk = Wk^T Wk  (64x64 tiles, 512 blocks)
    {
        GemmPtrs p{};
        p.A[0] = wqt; p.B[0] = wqt; p.Cb[0] = gq; p.scale[0] = 1.f;
        p.A[1] = wkt; p.B[1] = wkt; p.Cb[1] = gk; p.scale[1] = 1.f;
        gemm_big<0, 64, 64><<<dim3(EMBED / 64, EMBED / 64, 2), dim3(256), 0, stream>>>(
            p, EMBED, EMBED, EMBED);
    }
    // 3) Orth (z-batched): wqo = Wq - Wq*gk, wko = Wk - Wk*gq
    {
        GemmPtrs p{};
        p.A[0] = wq; p.B[0] = gk; p.D[0] = Wq; p.Cb[0] = wqo;
        p.A[1] = wk; p.B[1] = gq; p.D[1] = Wk; p.Cb[1] = wko;
        gemm_big<1, 64, 64><<<dim3(EMBED / 64, EMBED / 64, 2), dim3(256), 0, stream>>>(
            p, EMBED, EMBED, EMBED);
    }
    // 4) Projections (z-batched): q,k head-split; V transposed
    {
        GemmPtrs p{};
        p.A[0] = xq; p.B[0] = wqo; p.Cb[0] = qp; p.scale[0] = SCALE_Q; p.hs[0] = 1;
        p.A[1] = xk; p.B[1] = wko; p.Cb[1] = kp; p.scale[1] = 1.f;     p.hs[1] = 1;
        p.A[2] = xv; p.B[2] = wv;  p.Cb[2] = Vt; p.scale[2] = 1.f;     p.vt[2] = 1;
        gemm_big<0, 128, 128><<<dim3(EMBED / 128, MROWS / 128, 3), dim3(256), 0, stream>>>(
            p, MROWS, EMBED, EMBED);
    }
    // 5) Attention, no split-K (512 blocks, 1D XCD-swizzled grid), writes ao
    flash_attn8<<<dim3(SEQ / 128 * NHEADS * BATCH, 1, 1), dim3(256), 0, stream>>>(
        qp, kp, Vt, ao);
    // 6) Output projection (fp32 out), BM=64 for 512-block occupancy
    {
        GemmPtrs p{};
        p.A[0] = ao; p.B[0] = wo; p.Cf[0] = out; p.scale[0] = 1.f;
        gemm_big<2, 64, 128><<<dim3(EMBED / 128, MROWS / 64, 1), dim3(256), 0, stream>>>(
            p, MROWS, EMBED, EMBED);
    }
}

// Round 18
// 256.717 us; speedup vs baseline: 1.0678x; 1.0108x over previous
//
#include <hip/hip_runtime.h>
#include <math.h>

constexpr int EMBED  = 1024;
constexpr int NHEADS = 16;
constexpr int HDIM   = 64;
constexpr int BATCH  = 2;
constexpr int SEQ    = 2048;
constexpr int MROWS  = BATCH * SEQ;  // 4096

typedef unsigned short u16b;  // bf16 storage
typedef __attribute__((ext_vector_type(8))) short bfrag;   // 8 bf16 (4 VGPRs)
typedef __attribute__((ext_vector_type(4))) float ffrag;   // 4 fp32 acc
typedef __attribute__((ext_vector_type(16))) float f16frag; // 16 fp32 acc (32x32)
typedef __attribute__((ext_vector_type(4))) int i32x4;

// softmax scale folded with log2(e): exp(0.125*x) == exp2(0.18033688*x)
#define SCALE_Q 0.18033688f

__device__ __forceinline__ u16b f2b(float f) {          // RNE
    union { float f; unsigned u; } v; v.f = f;
    unsigned r = v.u + 0x7fffu + ((v.u >> 16) & 1u);
    return (u16b)(r >> 16);
}

__device__ __forceinline__ unsigned cvtpk_bf16(float a, float b) {
    unsigned r;
    asm("v_cvt_pk_bf16_f32 %0, %1, %2" : "=v"(r) : "v"(a), "v"(b));
    return r;
}

// permlane32_swap wrapper: returns {this_lane_word, swapped_word} as ints
__device__ __forceinline__ void plane_swap(unsigned a, unsigned b, int& lo, int& hi) {
    auto r = __builtin_amdgcn_permlane32_swap((int)a, (int)b, false, false);
    lo = (int)r[0];
    hi = (int)r[1];
}

__device__ __forceinline__ void gload_lds16(const u16b* g, u16b* l) {
    __builtin_amdgcn_global_load_lds(
        (const __attribute__((address_space(1))) void*)g,
        (__attribute__((address_space(3))) void*)l,
        16, 0, 0);
}

template<int N>
__device__ __forceinline__ void wait_vmcnt() {
    if constexpr (N == 0)      asm volatile("s_waitcnt vmcnt(0)" ::: "memory");
    else if constexpr (N == 2) asm volatile("s_waitcnt vmcnt(2)" ::: "memory");
    else if constexpr (N == 3) asm volatile("s_waitcnt vmcnt(3)" ::: "memory");
    else if constexpr (N == 4) asm volatile("s_waitcnt vmcnt(4)" ::: "memory");
    else static_assert(N == 0 || N == 2 || N == 3 || N == 4, "unsupported vmcnt");
}

struct GemmPtrs {
    const u16b* A[3];
    const u16b* B[3];
    const float* D[3];
    u16b* Cb[3];
    float* Cf[3];
    float scale[3];
    int vt[3];       // epilogue writes [B,H,64,S] (V-transposed)
    int hs[3];       // epilogue writes [B,H,S,64] (head-split)
};

// ---------- unified prep: z 0..2 inputs (convert), z 3..6 weights ----------
__global__ void prep_all(const float* __restrict__ q, const float* __restrict__ k,
                         const float* __restrict__ v,
                         const float* __restrict__ Wq, const float* __restrict__ Wk,
                         const float* __restrict__ Wv, const float* __restrict__ Wo,
                         u16b* __restrict__ oq, u16b* __restrict__ ok, u16b* __restrict__ ov,
                         u16b* __restrict__ wq, u16b* __restrict__ wk,
                         u16b* __restrict__ wv, u16b* __restrict__ wo,
                         u16b* __restrict__ wqt, u16b* __restrict__ wkt) {
    const int z = blockIdx.z;
    const int tid = threadIdx.x;
    if (z < 3) {
        const float* src = (z == 0) ? q : (z == 1) ? k : v;
        u16b* dst = (z == 0) ? oq : (z == 1) ? ok : ov;
        const int i = blockIdx.x * 256 + tid;
        float4 val = ((const float4*)src)[i];
        ushort4 o;
        o.x = f2b(val.x); o.y = f2b(val.y); o.z = f2b(val.z); o.w = f2b(val.w);
        ((ushort4*)dst)[i] = o;
        return;
    }
    if (blockIdx.x >= 1024) return;
    const int w = z - 3;
    const float* src = (w == 0) ? Wq : (w == 1) ? Wk : (w == 2) ? Wv : Wo;
    u16b* dst  = (w == 0) ? wq : (w == 1) ? wk : (w == 2) ? wv : wo;
    u16b* dstT = (w == 0) ? wqt : (w == 1) ? wkt : nullptr;
    __shared__ float t[32][33];
    const int bx = (blockIdx.x & 31) * 32, by = (blockIdx.x >> 5) * 32;
    const int x = tid & 31, y = tid >> 5;  // 32x8
#pragma unroll
    for (int r = 0; r < 4; ++r) {
        const int row = by + y + 8 * r;
        const float val = src[(size_t)row * EMBED + bx + x];
        dst[(size_t)row * EMBED + bx + x] = f2b(val);
        if (w < 2) t[y + 8 * r][x] = val;
    }
    if (w >= 2) return;
    __syncthreads();
#pragma unroll
    for (int r = 0; r < 4; ++r)
        dstT[(size_t)(bx + y + 8 * r) * EMBED + by + x] = f2b(t[x][y + 8 * r]);
}

// ---------- BM x BN bf16 MFMA NT GEMM, depth-2 prefetch + counted vmcnt ----------
// MODE 0: Cb = f2b(scale*AB)  (vt: [B,H,64,S] layout; hs: [B,H,S,64] layout)
// MODE 1: Cb = f2b(D - AB)
// MODE 2: Cf = AB (fp32)
template<int MODE, int BM, int BN>
__global__ __launch_bounds__(256) void gemm_big(GemmPtrs p, int M, int N, int K) {
    const int z = blockIdx.z;
    const u16b* __restrict__ A = p.A[z];
    const u16b* __restrict__ B = p.B[z];
    const float* __restrict__ D = p.D[z];
    u16b* __restrict__ Cb = p.Cb[z];
    float* __restrict__ Cf = p.Cf[z];
    const float scale = p.scale[z];
    const int vt = p.vt[z], hs = p.hs[z];

    constexpr int BK = 32;
    constexpr int IT = BM / 32;       // i-tiles per wave
    constexpr int JT = BN / 32;       // j-tiles per wave
    constexpr int IA = BM / 64;       // A staging issues per wave
    constexpr int IB = BN / 64;       // B staging issues per wave
    constexpr int LPW = IA + IB;      // per-wave loads per STAGE (vmcnt unit)
    __shared__ __align__(16) u16b As[2][BM * BK];
    __shared__ __align__(16) u16b Bs[2][BN * BK];

    const int tid = threadIdx.x;
    const int wave = tid >> 6, lane = tid & 63;
    const int quad = lane >> 4, l16 = lane & 15;
    const int wrow = wave >> 1, wcol = wave & 1;
    const int m0 = blockIdx.y * BM, n0 = blockIdx.x * BN;

    ffrag acc[IT][JT];
#pragma unroll
    for (int i = 0; i < IT; ++i)
#pragma unroll
        for (int j = 0; j < JT; ++j) acc[i][j] = ffrag{0.f, 0.f, 0.f, 0.f};

    const int srow = lane >> 2, schunk = lane & 3;

    // stage K-tile kt into buffer buf (LPW global_load_lds per wave)
    auto STAGE = [&](int buf, int kt) {
#pragma unroll
        for (int q = 0; q < IA; ++q) {
            int row = wave * (BM / 4) + q * 16;
            gload_lds16(A + (size_t)(m0 + row + srow) * K + kt + schunk * 8,
                        &As[buf][row * BK]);
        }
#pragma unroll
        for (int q = 0; q < IB; ++q) {
            int row = wave * (BN / 4) + q * 16;
            gload_lds16(B + (size_t)(n0 + row + srow) * K + kt + schunk * 8,
                        &Bs[buf][row * BK]);
        }
    };

    // prologue: tiles 0 and 1 in flight; wait only for tile 0
    STAGE(0, 0);
    STAGE(1, BK);
    wait_vmcnt<LPW>();
    __builtin_amdgcn_s_barrier();
    __builtin_amdgcn_sched_barrier(0);

    int cur = 0;
    for (int kt = 0; kt < K; kt += BK, cur ^= 1) {
        // 1) LDS -> regs for tile cur
        bfrag af[IT], bfv[JT];
#pragma unroll
        for (int i = 0; i < IT; ++i)
            af[i] = *(const bfrag*)&As[cur][(wrow * (BM / 2) + i * 16 + l16) * BK + quad * 8];
#pragma unroll
        for (int j = 0; j < JT; ++j)
            bfv[j] = *(const bfrag*)&Bs[cur][(wcol * (BN / 2) + j * 16 + l16) * BK + quad * 8];
        asm volatile("s_waitcnt lgkmcnt(0)" ::: "memory");
        __builtin_amdgcn_sched_barrier(0);
        __builtin_amdgcn_s_barrier();          // all waves done reading [cur]
        __builtin_amdgcn_sched_barrier(0);

        // 2) refill [cur] with tile t+2 (stays in flight across barriers)
        const bool stage = (kt + 2 * BK < K);
        if (stage) STAGE(cur, kt + 2 * BK);

        // 3) compute on regs — covers tile t+1's remaining latency
#pragma unroll
        for (int i = 0; i < IT; ++i)
#pragma unroll
            for (int j = 0; j < JT; ++j)
                acc[i][j] = __builtin_amdgcn_mfma_f32_16x16x32_bf16(af[i], bfv[j], acc[i][j], 0, 0, 0);

        // 4) tile t+1 (issued a full K-step ago) must be resident
        if (stage) wait_vmcnt<LPW>();
        else       wait_vmcnt<0>();
        __builtin_amdgcn_s_barrier();
        __builtin_amdgcn_sched_barrier(0);
    }

    if (MODE == 0 && vt) {
#pragma unroll
        for (int i = 0; i < IT; ++i)
#pragma unroll
            for (int j = 0; j < JT; ++j) {
                const int col = n0 + wcol * (BN / 2) + j * 16 + l16;
                const int h = col >> 6, d = col & 63;
                const int row0 = m0 + wrow * (BM / 2) + i * 16 + quad * 4;
                const int b = row0 >> 11, s = row0 & 2047;
                ushort4 o;
                o.x = f2b(acc[i][j][0]); o.y = f2b(acc[i][j][1]);
                o.z = f2b(acc[i][j][2]); o.w = f2b(acc[i][j][3]);
                *(ushort4*)&Cb[((size_t)(b * NHEADS + h) * HDIM + d) * SEQ + s] = o;
            }
        return;
    }
    if (MODE == 0 && hs) {
#pragma unroll
        for (int i = 0; i < IT; ++i)
#pragma unroll
        for (int j = 0; j < JT; ++j) {
                const int col = n0 + wcol * (BN / 2) + j * 16 + l16;
                const int h = col >> 6, d = col & 63;
                const int row0 = m0 + wrow * (BM / 2) + i * 16 + quad * 4;
                const int b = row0 >> 11, s0 = row0 & 2047;
#pragma unroll
                for (int r = 0; r < 4; ++r)
                    Cb[((size_t)(b * NHEADS + h) * SEQ + s0 + r) * HDIM + d] =
                        f2b(acc[i][j][r] * scale);
            }
        return;
    }

#pragma unroll
    for (int i = 0; i < IT; ++i)
#pragma unroll
        for (int j = 0; j < JT; ++j) {
            const int col = n0 + wcol * (BN / 2) + j * 16 + l16;
#pragma unroll
            for (int r = 0; r < 4; ++r) {
                const int row = m0 + wrow * (BM / 2) + i * 16 + quad * 4 + r;
                const size_t idx = (size_t)row * N + col;
                const float v = acc[i][j][r];
                if (MODE == 0) Cb[idx] = f2b(v * scale);
                else if (MODE == 1) Cb[idx] = f2b(D[idx] - v);
                else Cf[idx] = v;
            }
        }
}

// ---------- flash attention v9: 128-key tiles, half the barriers ----------
// qp,kp: [B,H,S,64] bf16 (q pre-scaled); Vt: [B,H,64,S]. ao: [B,S,E] bf16.
// 512 blocks (32 (b,h)-groups x 16 q-tiles), each walks all 2048 keys in
// 16 iterations of 128 keys (two barrier-free 64-key halves per iter) ->
// halves the __syncthreads/drain count vs v8 and gives the scheduler two
// independent QK/softmax/PV streams to interleave.
// LDS 64 KB: Ks[2][128x64], Vs[2][64x128] -> still 2 blocks/CU (grid-limited).
// Max-free softmax => final O = O_acc / l in epilogue (exact).
// XCD swizzle: group's low 3 bits = n&7 (r16: FETCH 71.7->16.4 MB).
// LDS staging is the coalescing layer (v7 no-LDS regressed 131 us, r12).
// setprio: null (r15).
__global__ __launch_bounds__(256) void flash_attn9(
    const u16b* __restrict__ Qp, const u16b* __restrict__ Kp,
    const u16b* __restrict__ Vt, u16b* __restrict__ ao)
{
    const int tid = threadIdx.x;
    const int wave = tid >> 6, lane = tid & 63;
    const int l32 = lane & 31, hi = lane >> 5;

    // bijective XCD swizzle: n -> (group g, q-tile qt), g's low 3 bits = n&7
    const int n = blockIdx.x;          // 0..511
    const int xcd = n & 7, t = n >> 3; // t: 0..63
    const int qt = t & 15;
    const int g = ((t >> 4) << 3) | xcd;   // 0..31
    const int b = g >> 4;                   // 0..1
    const int h = g & 15;                   // 0..15

    const int qb = qt * 128 + wave * 32;

    __shared__ __align__(16) u16b Ks[2][128 * 64];   // [key][d], swizzled
    __shared__ __align__(16) u16b Vs[2][64 * 128];   // [d][key], swizzled

    const size_t hsbase = (size_t)(b * NHEADS + h) * SEQ;
    const size_t vtbase = (size_t)(b * NHEADS + h) * HDIM * SEQ;

    // Q fragments: B-operand of 32x32x16 (col=q=l32, k = ks*16 + hi*8 + j)
    bfrag bq[4];
#pragma unroll
    for (int ks = 0; ks < 4; ++ks)
        bq[ks] = *(const bfrag*)&Qp[(hsbase + qb + l32) * HDIM + ks * 16 + hi * 8];

    f16frag ov0, ov1;   // O^T rows d=0..31 / 32..63, col q=l32
#pragma unroll
    for (int r = 0; r < 16; ++r) { ov0[r] = 0.f; ov1[r] = 0.f; }
    float l_run = 0.f;

    // per-thread staging indices (4 K-bfrags + 4 V-bfrags per 128-key tile)
    int swzK[4], swzV[4];
    size_t srcV[4];
#pragma unroll
    for (int i = 0; i < 4; ++i) {
        const int f = tid + 256 * i;
        const int key = f >> 3, chk = f & 7;          // K: [128 keys][8 chunks]
        swzK[i] = (key * 8 + (chk ^ (key & 7))) * 8;
        const int dV = f >> 4, cV = f & 15;           // V: [64 d][16 chunks]
        swzV[i] = (dV * 16 + (cV ^ (dV & 7))) * 8;
        srcV[i] = (size_t)dV * SEQ + cV * 8;
    }

    const u16b* kgb = Kp + hsbase * HDIM;
    const u16b* vgb = Vt + vtbase;

    // stage first 128-key tile -> buf 0
    {
        bfrag kk[4], vv[4];
#pragma unroll
        for (int i = 0; i < 4; ++i) {
            kk[i] = *(const bfrag*)(kgb + (size_t)(tid + 256 * i) * 8);
            vv[i] = *(const bfrag*)(vgb + srcV[i]);
        }
#pragma unroll
        for (int i = 0; i < 4; ++i) {
            *(bfrag*)&Ks[0][swzK[i]] = kk[i];
            *(bfrag*)&Vs[0][swzV[i]] = vv[i];
        }
    }
    __syncthreads();

    int p = 0;
    for (int kt = 0; kt < SEQ; kt += 128, p ^= 1) {
        const bool more = (kt + 128) < SEQ;
        bfrag kn[4], vn[4];
        if (more) {
            const u16b* kg = kgb + (size_t)(kt + 128) * HDIM;
#pragma unroll
            for (int i = 0; i < 4; ++i) {
                kn[i] = *(const bfrag*)(kg + (size_t)(tid + 256 * i) * 8);
                vn[i] = *(const bfrag*)(vgb + srcV[i] + kt + 128);
            }
        }

#pragma unroll
        for (int half = 0; half < 2; ++half) {
            const int rb = half * 64;     // key row base in Ks
            const int cb = half * 8;      // V chunk base in Vs

            // --- S^T = K Q^T : two 32x32 tiles (keys rb..rb+31, rb+32..rb+63) ---
            f16frag St0, St1;
#pragma unroll
            for (int r = 0; r < 16; ++r) { St0[r] = 0.f; St1[r] = 0.f; }
#pragma unroll
            for (int ks = 0; ks < 4; ++ks) {
                const int ch = ks * 2 + hi;
                bfrag k0 = *(const bfrag*)&Ks[p][((rb + l32) * 8 + (ch ^ (l32 & 7))) * 8];
                bfrag k1 = *(const bfrag*)&Ks[p][((rb + 32 + l32) * 8 + (ch ^ (l32 & 7))) * 8];
                St0 = __builtin_amdgcn_mfma_f32_32x32x16_bf16(k0, bq[ks], St0, 0, 0, 0);
                St1 = __builtin_amdgcn_mfma_f32_32x32x16_bf16(k1, bq[ks], St1, 0, 0, 0);
            }

            // --- max-free softmax: exp2 all, column sum for q=l32 ---
            float rs = 0.f;
#pragma unroll
            for (int r = 0; r < 16; ++r) {
                const float a = __builtin_amdgcn_exp2f(St0[r]);
                const float c = __builtin_amdgcn_exp2f(St1[r]);
                St0[r] = a; St1[r] = c;
                rs += a + c;
            }
            rs += __shfl_xor(rs, 32);
            l_run += rs;

            // --- P -> bf16 B-operands fully in-register ---
            unsigned d0[8], d1[8];
#pragma unroll
            for (int rr = 0; rr < 8; ++rr) {
                d0[rr] = cvtpk_bf16(St0[2 * rr], St0[2 * rr + 1]);
                d1[rr] = cvtpk_bf16(St1[2 * rr], St1[2 * rr + 1]);
            }
            bfrag bp[4];
            {
                int a0, a1, b0, b1, c0w, c1, e0, e1;
                plane_swap(d0[0], d0[2], a0, a1);
                plane_swap(d0[1], d0[3], b0, b1);
                i32x4 w = { a0, b0, a1, b1 };
                bp[0] = __builtin_bit_cast(bfrag, w);
                plane_swap(d0[4], d0[6], c0w, c1);
                plane_swap(d0[5], d0[7], e0, e1);
                i32x4 w2 = { c0w, e0, c1, e1 };
                bp[1] = __builtin_bit_cast(bfrag, w2);
            }
            {
                int a0, a1, b0, b1, c0w, c1, e0, e1;
                plane_swap(d1[0], d1[2], a0, a1);
                plane_swap(d1[1], d1[3], b0, b1);
                i32x4 w = { a0, b0, a1, b1 };
                bp[2] = __builtin_bit_cast(bfrag, w);
                plane_swap(d1[4], d1[6], c0w, c1);
                plane_swap(d1[5], d1[7], e0, e1);
                i32x4 w2 = { c0w, e0, c1, e1 };
                bp[3] = __builtin_bit_cast(bfrag, w2);
            }

            // --- O^T += V^T P : two 32-d tiles x 4 key-steps of 16 ---
#pragma unroll
            for (int ks = 0; ks < 4; ++ks) {
                const int ch = cb + ks * 2 + hi;
                bfrag v0 = *(const bfrag*)&Vs[p][(l32 * 16 + (ch ^ (l32 & 7))) * 8];
                bfrag v1 = *(const bfrag*)&Vs[p][((32 + l32) * 16 + (ch ^ (l32 & 7))) * 8];
                ov0 = __builtin_amdgcn_mfma_f32_32x32x16_bf16(v0, bp[ks], ov0, 0, 0, 0);
                ov1 = __builtin_amdgcn_mfma_f32_32x32x16_bf16(v1, bp[ks], ov1, 0, 0, 0);
            }
        }

        if (more) {
#pragma unroll
            for (int i = 0; i < 4; ++i) {
                *(bfrag*)&Ks[p ^ 1][swzK[i]] = kn[i];
                *(bfrag*)&Vs[p ^ 1][swzV[i]] = vn[i];
            }
            __syncthreads();
        }
    }

    // epilogue: O = O_acc / l, written directly as bf16 [B,S,E]
    // ov reg r -> d = (r&3) + 8*(r>>2) + 4*hi (+32 for ov1), q = l32
    const float inv = 1.f / l_run;
    const size_t orow = ((size_t)b * SEQ + qb + l32) * EMBED + h * HDIM;
#pragma unroll
    for (int rr = 0; rr < 4; ++rr) {
        ushort4 o0, o1;
        o0.x = f2b(ov0[4 * rr + 0] * inv); o0.y = f2b(ov0[4 * rr + 1] * inv);
        o0.z = f2b(ov0[4 * rr + 2] * inv); o0.w = f2b(ov0[4 * rr + 3] * inv);
        o1.x = f2b(ov1[4 * rr + 0] * inv); o1.y = f2b(ov1[4 * rr + 1] * inv);
        o1.z = f2b(ov1[4 * rr + 2] * inv); o1.w = f2b(ov1[4 * rr + 3] * inv);
        *(ushort4*)&ao[orow + rr * 8 + hi * 4] = o0;
        *(ushort4*)&ao[orow + 32 + rr * 8 + hi * 4] = o1;
    }
}

// ---------- launch ----------
extern "C" void kernel_launch(void* const* d_in, const int* in_sizes, int n_in,
                              void* d_out, int out_size, void* d_ws, size_t ws_size,
                              hipStream_t stream) {
    const float* query = (const float*)d_in[0];
    const float* key_  = (const float*)d_in[1];
    const float* value = (const float*)d_in[2];
    const float* Wq    = (const float*)d_in[3];
    const float* Wk    = (const float*)d_in[4];
    const float* Wv    = (const float*)d_in[5];
    const float* Wo    = (const float*)d_in[6];
    float* out = (float*)d_out;

    char* ws = (char*)d_ws;
    const size_t MB = 1024 * 1024;
    u16b* xq  = (u16b*)(ws + 0 * MB);    // 8 MB, dead after proj
    u16b* xk  = (u16b*)(ws + 8 * MB);    // dead after proj
    u16b* xv  = (u16b*)(ws + 16 * MB);   // dead after proj
    u16b* wq  = (u16b*)(ws + 24 * MB);   // dead after orth
    u16b* wk  = (u16b*)(ws + 26 * MB);   // dead after orth
    u16b* wv  = (u16b*)(ws + 28 * MB);   // dead after proj
    u16b* gq  = (u16b*)(ws + 32 * MB);   // dead after orth
    u16b* gk  = (u16b*)(ws + 34 * MB);   // dead after orth
    u16b* wqo = (u16b*)(ws + 36 * MB);   // dead after proj
    u16b* wko = (u16b*)(ws + 38 * MB);   // dead after proj
    u16b* wo  = (u16b*)(ws + 40 * MB);   // live until out-proj
    u16b* qp  = (u16b*)(ws + 44 * MB);   // [B,H,S,64], dead after attn
    u16b* kp  = (u16b*)(ws + 52 * MB);   // dead after attn
    u16b* Vt  = (u16b*)(ws + 60 * MB);   // [B,H,64,S], dead after attn
    u16b* wqt = (u16b*)(ws + 60 * MB);   // inside Vt region: dead after gram, Vt written later
    u16b* wkt = (u16b*)(ws + 62 * MB);
    u16b* ao  = (u16b*)(ws + 0 * MB);    // attn output [B,S,E] bf16 over dead xq

    // 1) unified prep (inputs + weights)
    prep_all<<<dim3(MROWS * EMBED / 1024, 1, 7), dim3(256), 0, stream>>>(
        query, key_, value, Wq, Wk, Wv, Wo,
        xq, xk, xv, wq, wk, wv, wo, wqt, wkt);

    // 2) Grams (z-batched): gq = Wq^T Wq, gk = Wk^T Wk  (64x64 tiles, 512 blocks)
    {
        GemmPtrs p{};
        p.A[0] = wqt; p.B[0] = wqt; p.Cb[0] = gq; p.scale[0] = 1.f;
        p.A[1] = wkt; p.B[1] = wkt; p.Cb[1] = gk; p.scale[1] = 1.f;
        gemm_big<0, 64, 64><<<dim3(EMBED / 64, EMBED / 64, 2), dim3(256), 0, stream>>>(
            p, EMBED, EMBED, EMBED);
    }
    // 3) Orth (z-batched): wqo = Wq - Wq*gk, wko = Wk - Wk*gq
    {
        GemmPtrs p{};
        p.A[0] = wq; p.B[0] = gk; p.D[0] = Wq; p.Cb[0] = wqo;
        p.A[1] = wk; p.B[1] = gq; p.D[1] = Wk; p.Cb[1] = wko;
        gemm_big<1, 64, 64><<<dim3(EMBED / 64, EMBED / 64, 2), dim3(256), 0, stream>>>(
            p, EMBED, EMBED, EMBED);
    }
    // 4) Projections (z-batched): q,k head-split; V transposed
    {
        GemmPtrs p{};
        p.A[0] = xq; p.B[0] = wqo; p.Cb[0] = qp; p.scale[0] = SCALE_Q; p.hs[0] = 1;
        p.A[1] = xk; p.B[1] = wko; p.Cb[1] = kp; p.scale[1] = 1.f;     p.hs[1] = 1;
        p.A[2] = xv; p.B[2] = wv;  p.Cb[2] = Vt; p.scale[2] = 1.f;     p.vt[2] = 1;
        gemm_big<0, 128, 128><<<dim3(EMBED / 128, MROWS / 128, 3), dim3(256), 0, stream>>>(
            p, MROWS, EMBED, EMBED);
    }
    // 5) Attention, no split-K (512 blocks, 1D XCD-swizzled grid), writes ao
    flash_attn9<<<dim3(SEQ / 128 * NHEADS * BATCH, 1, 1), dim3(256), 0, stream>>>(
        qp, kp, Vt, ao);
    // 6) Output projection (fp32 out), BM=64 for 512-block occupancy
    {
        GemmPtrs p{};
        p.A[0] = ao; p.B[0] = wo; p.Cf[0] = out; p.scale[0] = 1.f;
        gemm_big<2, 64, 128><<<dim3(EMBED / 128, MROWS / 64, 1), dim3(256), 0, stream>>>(
            p, MROWS, EMBED, EMBED);
    }
}

// Round 19
// 248.472 us; speedup vs baseline: 1.1032x; 1.0332x over previous
//
#include <hip/hip_runtime.h>
#include <math.h>

constexpr int EMBED  = 1024;
constexpr int NHEADS = 16;
constexpr int HDIM   = 64;
constexpr int BATCH  = 2;
constexpr int SEQ    = 2048;
constexpr int MROWS  = BATCH * SEQ;  // 4096

typedef unsigned short u16b;  // bf16 storage
typedef __attribute__((ext_vector_type(8))) short bfrag;   // 8 bf16 (4 VGPRs)
typedef __attribute__((ext_vector_type(4))) float ffrag;   // 4 fp32 acc
typedef __attribute__((ext_vector_type(16))) float f16frag; // 16 fp32 acc (32x32)
typedef __attribute__((ext_vector_type(4))) int i32x4;

// softmax scale folded with log2(e): exp(0.125*x) == exp2(0.18033688*x)
#define SCALE_Q 0.18033688f

__device__ __forceinline__ u16b f2b(float f) {          // RNE
    union { float f; unsigned u; } v; v.f = f;
    unsigned r = v.u + 0x7fffu + ((v.u >> 16) & 1u);
    return (u16b)(r >> 16);
}

__device__ __forceinline__ unsigned cvtpk_bf16(float a, float b) {
    unsigned r;
    asm("v_cvt_pk_bf16_f32 %0, %1, %2" : "=v"(r) : "v"(a), "v"(b));
    return r;
}

// permlane32_swap wrapper: returns {this_lane_word, swapped_word} as ints
__device__ __forceinline__ void plane_swap(unsigned a, unsigned b, int& lo, int& hi) {
    auto r = __builtin_amdgcn_permlane32_swap((int)a, (int)b, false, false);
    lo = (int)r[0];
    hi = (int)r[1];
}

__device__ __forceinline__ void gload_lds16(const u16b* g, u16b* l) {
    __builtin_amdgcn_global_load_lds(
        (const __attribute__((address_space(1))) void*)g,
        (__attribute__((address_space(3))) void*)l,
        16, 0, 0);
}

template<int N>
__device__ __forceinline__ void wait_vmcnt() {
    if constexpr (N == 0)      asm volatile("s_waitcnt vmcnt(0)" ::: "memory");
    else if constexpr (N == 2) asm volatile("s_waitcnt vmcnt(2)" ::: "memory");
    else if constexpr (N == 3) asm volatile("s_waitcnt vmcnt(3)" ::: "memory");
    else if constexpr (N == 4) asm volatile("s_waitcnt vmcnt(4)" ::: "memory");
    else static_assert(N == 0 || N == 2 || N == 3 || N == 4, "unsupported vmcnt");
}

struct GemmPtrs {
    const u16b* A[3];
    const u16b* B[3];
    const float* D[3];
    u16b* Cb[3];
    float* Cf[3];
    float scale[3];
    int vt[3];       // epilogue writes [B,H,64,S] (V-transposed)
    int hs[3];       // epilogue writes [B,H,S,64] (head-split)
};

// ---------- unified prep: z 0..2 inputs (convert), z 3..6 weights ----------
__global__ void prep_all(const float* __restrict__ q, const float* __restrict__ k,
                         const float* __restrict__ v,
                         const float* __restrict__ Wq, const float* __restrict__ Wk,
                         const float* __restrict__ Wv, const float* __restrict__ Wo,
                         u16b* __restrict__ oq, u16b* __restrict__ ok, u16b* __restrict__ ov,
                         u16b* __restrict__ wq, u16b* __restrict__ wk,
                         u16b* __restrict__ wv, u16b* __restrict__ wo,
                         u16b* __restrict__ wqt, u16b* __restrict__ wkt) {
    const int z = blockIdx.z;
    const int tid = threadIdx.x;
    if (z < 3) {
        const float* src = (z == 0) ? q : (z == 1) ? k : v;
        u16b* dst = (z == 0) ? oq : (z == 1) ? ok : ov;
        const int i = blockIdx.x * 256 + tid;
        float4 val = ((const float4*)src)[i];
        ushort4 o;
        o.x = f2b(val.x); o.y = f2b(val.y); o.z = f2b(val.z); o.w = f2b(val.w);
        ((ushort4*)dst)[i] = o;
        return;
    }
    if (blockIdx.x >= 1024) return;
    const int w = z - 3;
    const float* src = (w == 0) ? Wq : (w == 1) ? Wk : (w == 2) ? Wv : Wo;
    u16b* dst  = (w == 0) ? wq : (w == 1) ? wk : (w == 2) ? wv : wo;
    u16b* dstT = (w == 0) ? wqt : (w == 1) ? wkt : nullptr;
    __shared__ float t[32][33];
    const int bx = (blockIdx.x & 31) * 32, by = (blockIdx.x >> 5) * 32;
    const int x = tid & 31, y = tid >> 5;  // 32x8
#pragma unroll
    for (int r = 0; r < 4; ++r) {
        const int row = by + y + 8 * r;
        const float val = src[(size_t)row * EMBED + bx + x];
        dst[(size_t)row * EMBED + bx + x] = f2b(val);
        if (w < 2) t[y + 8 * r][x] = val;
    }
    if (w >= 2) return;
    __syncthreads();
#pragma unroll
    for (int r = 0; r < 4; ++r)
        dstT[(size_t)(bx + y + 8 * r) * EMBED + by + x] = f2b(t[x][y + 8 * r]);
}

// ---------- BM x BN bf16 MFMA NT GEMM, depth-2 prefetch + counted vmcnt ----------
// MODE 0: Cb = f2b(scale*AB)  (vt: [B,H,64,S] layout; hs: [B,H,S,64] layout)
// MODE 1: Cb = f2b(D - AB)
// MODE 2: Cf = AB (fp32)
// GM (grid mode): 0 = plain 3D grid; 1/2/3 = 1D XCD-rectangle swizzles:
//   1: proj   (x8, y32, z3)  -> 4x*8y  per XCD per z (A 2MB + B 1MB < 4MB L2)
//   2: outproj(x8, y64)      -> 4x*16y per XCD       (A 2MB + B 1MB)
//   3: gram   (x16, y16, z2) -> 4x*8y  per XCD per z (A 1MB + B .5MB)
template<int MODE, int BM, int BN, int GM>
__global__ __launch_bounds__(256) void gemm_big(GemmPtrs p, int M, int N, int K) {
    int bx, by, bz;
    if constexpr (GM == 0) {
        bx = blockIdx.x; by = blockIdx.y; bz = blockIdx.z;
    } else {
        const int n = blockIdx.x, c = n & 7, k = n >> 3;
        if constexpr (GM == 1) {
            bx = ((c >> 2) << 2) | (k & 3);
            by = ((c & 3) << 3) | ((k >> 2) & 7);
            bz = k >> 5;
        } else if constexpr (GM == 2) {
            bx = ((c >> 2) << 2) | (k & 3);
            by = ((c & 3) << 4) | (k >> 2);
            bz = 0;
        } else {  // GM == 3
            bx = ((c >> 1) << 2) | (k & 3);
            by = ((c & 1) << 3) | ((k >> 2) & 7);
            bz = k >> 5;
        }
    }
    const int z = bz;
    const u16b* __restrict__ A = p.A[z];
    const u16b* __restrict__ B = p.B[z];
    const float* __restrict__ D = p.D[z];
    u16b* __restrict__ Cb = p.Cb[z];
    float* __restrict__ Cf = p.Cf[z];
    const float scale = p.scale[z];
    const int vt = p.vt[z], hs = p.hs[z];

    constexpr int BK = 32;
    constexpr int IT = BM / 32;       // i-tiles per wave
    constexpr int JT = BN / 32;       // j-tiles per wave
    constexpr int IA = BM / 64;       // A staging issues per wave
    constexpr int IB = BN / 64;       // B staging issues per wave
    constexpr int LPW = IA + IB;      // per-wave loads per STAGE (vmcnt unit)
    __shared__ __align__(16) u16b As[2][BM * BK];
    __shared__ __align__(16) u16b Bs[2][BN * BK];

    const int tid = threadIdx.x;
    const int wave = tid >> 6, lane = tid & 63;
    const int quad = lane >> 4, l16 = lane & 15;
    const int wrow = wave >> 1, wcol = wave & 1;
    const int m0 = by * BM, n0 = bx * BN;

    ffrag acc[IT][JT];
#pragma unroll
    for (int i = 0; i < IT; ++i)
#pragma unroll
        for (int j = 0; j < JT; ++j) acc[i][j] = ffrag{0.f, 0.f, 0.f, 0.f};

    const int srow = lane >> 2, schunk = lane & 3;

    // stage K-tile kt into buffer buf (LPW global_load_lds per wave)
    auto STAGE = [&](int buf, int kt) {
#pragma unroll
        for (int q = 0; q < IA; ++q) {
            int row = wave * (BM / 4) + q * 16;
            gload_lds16(A + (size_t)(m0 + row + srow) * K + kt + schunk * 8,
                        &As[buf][row * BK]);
        }
#pragma unroll
        for (int q = 0; q < IB; ++q) {
            int row = wave * (BN / 4) + q * 16;
            gload_lds16(B + (size_t)(n0 + row + srow) * K + kt + schunk * 8,
                        &Bs[buf][row * BK]);
        }
    };

    // prologue: tiles 0 and 1 in flight; wait only for tile 0
    STAGE(0, 0);
    STAGE(1, BK);
    wait_vmcnt<LPW>();
    __builtin_amdgcn_s_barrier();
    __builtin_amdgcn_sched_barrier(0);

    int cur = 0;
    for (int kt = 0; kt < K; kt += BK, cur ^= 1) {
        // 1) LDS -> regs for tile cur
        bfrag af[IT], bfv[JT];
#pragma unroll
        for (int i = 0; i < IT; ++i)
            af[i] = *(const bfrag*)&As[cur][(wrow * (BM / 2) + i * 16 + l16) * BK + quad * 8];
#pragma unroll
        for (int j = 0; j < JT; ++j)
            bfv[j] = *(const bfrag*)&Bs[cur][(wcol * (BN / 2) + j * 16 + l16) * BK + quad * 8];
        asm volatile("s_waitcnt lgkmcnt(0)" ::: "memory");
        __builtin_amdgcn_sched_barrier(0);
        __builtin_amdgcn_s_barrier();          // all waves done reading [cur]
        __builtin_amdgcn_sched_barrier(0);

        // 2) refill [cur] with tile t+2 (stays in flight across barriers)
        const bool stage = (kt + 2 * BK < K);
        if (stage) STAGE(cur, kt + 2 * BK);

        // 3) compute on regs — covers tile t+1's remaining latency
#pragma unroll
        for (int i = 0; i < IT; ++i)
#pragma unroll
            for (int j = 0; j < JT; ++j)
                acc[i][j] = __builtin_amdgcn_mfma_f32_16x16x32_bf16(af[i], bfv[j], acc[i][j], 0, 0, 0);

        // 4) tile t+1 (issued a full K-step ago) must be resident
        if (stage) wait_vmcnt<LPW>();
        else       wait_vmcnt<0>();
        __builtin_amdgcn_s_barrier();
        __builtin_amdgcn_sched_barrier(0);
    }

    if (MODE == 0 && vt) {
#pragma unroll
        for (int i = 0; i < IT; ++i)
#pragma unroll
            for (int j = 0; j < JT; ++j) {
                const int col = n0 + wcol * (BN / 2) + j * 16 + l16;
                const int h = col >> 6, d = col & 63;
                const int row0 = m0 + wrow * (BM / 2) + i * 16 + quad * 4;
                const int b = row0 >> 11, s = row0 & 2047;
                ushort4 o;
                o.x = f2b(acc[i][j][0]); o.y = f2b(acc[i][j][1]);
                o.z = f2b(acc[i][j][2]); o.w = f2b(acc[i][j][3]);
                *(ushort4*)&Cb[((size_t)(b * NHEADS + h) * HDIM + d) * SEQ + s] = o;
            }
        return;
    }
    if (MODE == 0 && hs) {
#pragma unroll
        for (int i = 0; i < IT; ++i)
#pragma unroll
        for (int j = 0; j < JT; ++j) {
                const int col = n0 + wcol * (BN / 2) + j * 16 + l16;
                const int h = col >> 6, d = col & 63;
                const int row0 = m0 + wrow * (BM / 2) + i * 16 + quad * 4;
                const int b = row0 >> 11, s0 = row0 & 2047;
#pragma unroll
                for (int r = 0; r < 4; ++r)
                    Cb[((size_t)(b * NHEADS + h) * SEQ + s0 + r) * HDIM + d] =
                        f2b(acc[i][j][r] * scale);
            }
        return;
    }

#pragma unroll
    for (int i = 0; i < IT; ++i)
#pragma unroll
        for (int j = 0; j < JT; ++j) {
            const int col = n0 + wcol * (BN / 2) + j * 16 + l16;
#pragma unroll
            for (int r = 0; r < 4; ++r) {
                const int row = m0 + wrow * (BM / 2) + i * 16 + quad * 4 + r;
                const size_t idx = (size_t)row * N + col;
                const float v = acc[i][j][r];
                if (MODE == 0) Cb[idx] = f2b(v * scale);
                else if (MODE == 1) Cb[idx] = f2b(D[idx] - v);
                else Cf[idx] = v;
            }
        }
}

// ---------- flash attention v9: 128-key tiles, no split-K ----------
// qp,kp: [B,H,S,64] bf16 (q pre-scaled); Vt: [B,H,64,S]. ao: [B,S,E] bf16.
// 512 blocks (32 (b,h)-groups x 16 q-tiles), 16 iters of 128 keys.
// Max-free softmax => final O = O_acc / l in epilogue (exact).
// XCD swizzle: group's low 3 bits = n&7 (r16: FETCH 71.7->16.4 MB).
// LDS staging is the coalescing layer (v7 no-LDS regressed 131 us, r12).
// setprio: null (r15). Barrier-halving: null (r18) -> chain-bound plateau.
__global__ __launch_bounds__(256) void flash_attn9(
    const u16b* __restrict__ Qp, const u16b* __restrict__ Kp,
    const u16b* __restrict__ Vt, u16b* __restrict__ ao)
{
    const int tid = threadIdx.x;
    const int wave = tid >> 6, lane = tid & 63;
    const int l32 = lane & 31, hi = lane >> 5;

    // bijective XCD swizzle: n -> (group g, q-tile qt), g's low 3 bits = n&7
    const int n = blockIdx.x;          // 0..511
    const int xcd = n & 7, t = n >> 3; // t: 0..63
    const int qt = t & 15;
    const int g = ((t >> 4) << 3) | xcd;   // 0..31
    const int b = g >> 4;                   // 0..1
    const int h = g & 15;                   // 0..15

    const int qb = qt * 128 + wave * 32;

    __shared__ __align__(16) u16b Ks[2][128 * 64];   // [key][d], swizzled
    __shared__ __align__(16) u16b Vs[2][64 * 128];   // [d][key], swizzled

    const size_t hsbase = (size_t)(b * NHEADS + h) * SEQ;
    const size_t vtbase = (size_t)(b * NHEADS + h) * HDIM * SEQ;

    // Q fragments: B-operand of 32x32x16 (col=q=l32, k = ks*16 + hi*8 + j)
    bfrag bq[4];
#pragma unroll
    for (int ks = 0; ks < 4; ++ks)
        bq[ks] = *(const bfrag*)&Qp[(hsbase + qb + l32) * HDIM + ks * 16 + hi * 8];

    f16frag ov0, ov1;   // O^T rows d=0..31 / 32..63, col q=l32
#pragma unroll
    for (int r = 0; r < 16; ++r) { ov0[r] = 0.f; ov1[r] = 0.f; }
    float l_run = 0.f;

    // per-thread staging indices (4 K-bfrags + 4 V-bfrags per 128-key tile)
    int swzK[4], swzV[4];
    size_t srcV[4];
#pragma unroll
    for (int i = 0; i < 4; ++i) {
        const int f = tid + 256 * i;
        const int key = f >> 3, chk = f & 7;          // K: [128 keys][8 chunks]
        swzK[i] = (key * 8 + (chk ^ (key & 7))) * 8;
        const int dV = f >> 4, cV = f & 15;           // V: [64 d][16 chunks]
        swzV[i] = (dV * 16 + (cV ^ (dV & 7))) * 8;
        srcV[i] = (size_t)dV * SEQ + cV * 8;
    }

    const u16b* kgb = Kp + hsbase * HDIM;
    const u16b* vgb = Vt + vtbase;

    // stage first 128-key tile -> buf 0
    {
        bfrag kk[4], vv[4];
#pragma unroll
        for (int i = 0; i < 4; ++i) {
            kk[i] = *(const bfrag*)(kgb + (size_t)(tid + 256 * i) * 8);
            vv[i] = *(const bfrag*)(vgb + srcV[i]);
        }
#pragma unroll
        for (int i = 0; i < 4; ++i) {
            *(bfrag*)&Ks[0][swzK[i]] = kk[i];
            *(bfrag*)&Vs[0][swzV[i]] = vv[i];
        }
    }
    __syncthreads();

    int p = 0;
    for (int kt = 0; kt < SEQ; kt += 128, p ^= 1) {
        const bool more = (kt + 128) < SEQ;
        bfrag kn[4], vn[4];
        if (more) {
            const u16b* kg = kgb + (size_t)(kt + 128) * HDIM;
#pragma unroll
            for (int i = 0; i < 4; ++i) {
                kn[i] = *(const bfrag*)(kg + (size_t)(tid + 256 * i) * 8);
                vn[i] = *(const bfrag*)(vgb + srcV[i] + kt + 128);
            }
        }

#pragma unroll
        for (int half = 0; half < 2; ++half) {
            const int rb = half * 64;     // key row base in Ks
            const int cb = half * 8;      // V chunk base in Vs

            // --- S^T = K Q^T : two 32x32 tiles (keys rb..rb+31, rb+32..rb+63) ---
            f16frag St0, St1;
#pragma unroll
            for (int r = 0; r < 16; ++r) { St0[r] = 0.f; St1[r] = 0.f; }
#pragma unroll
            for (int ks = 0; ks < 4; ++ks) {
                const int ch = ks * 2 + hi;
                bfrag k0 = *(const bfrag*)&Ks[p][((rb + l32) * 8 + (ch ^ (l32 & 7))) * 8];
                bfrag k1 = *(const bfrag*)&Ks[p][((rb + 32 + l32) * 8 + (ch ^ (l32 & 7))) * 8];
                St0 = __builtin_amdgcn_mfma_f32_32x32x16_bf16(k0, bq[ks], St0, 0, 0, 0);
                St1 = __builtin_amdgcn_mfma_f32_32x32x16_bf16(k1, bq[ks], St1, 0, 0, 0);
            }

            // --- max-free softmax: exp2 all, column sum for q=l32 ---
            float rs = 0.f;
#pragma unroll
            for (int r = 0; r < 16; ++r) {
                const float a = __builtin_amdgcn_exp2f(St0[r]);
                const float c = __builtin_amdgcn_exp2f(St1[r]);
                St0[r] = a; St1[r] = c;
                rs += a + c;
            }
            rs += __shfl_xor(rs, 32);
            l_run += rs;

            // --- P -> bf16 B-operands fully in-register ---
            unsigned d0[8], d1[8];
#pragma unroll
            for (int rr = 0; rr < 8; ++rr) {
                d0[rr] = cvtpk_bf16(St0[2 * rr], St0[2 * rr + 1]);
                d1[rr] = cvtpk_bf16(St1[2 * rr], St1[2 * rr + 1]);
            }
            bfrag bp[4];
            {
                int a0, a1, b0, b1, c0w, c1, e0, e1;
                plane_swap(d0[0], d0[2], a0, a1);
                plane_swap(d0[1], d0[3], b0, b1);
                i32x4 w = { a0, b0, a1, b1 };
                bp[0] = __builtin_bit_cast(bfrag, w);
                plane_swap(d0[4], d0[6], c0w, c1);
                plane_swap(d0[5], d0[7], e0, e1);
                i32x4 w2 = { c0w, e0, c1, e1 };
                bp[1] = __builtin_bit_cast(bfrag, w2);
            }
            {
                int a0, a1, b0, b1, c0w, c1, e0, e1;
                plane_swap(d1[0], d1[2], a0, a1);
                plane_swap(d1[1], d1[3], b0, b1);
                i32x4 w = { a0, b0, a1, b1 };
                bp[2] = __builtin_bit_cast(bfrag, w);
                plane_swap(d1[4], d1[6], c0w, c1);
                plane_swap(d1[5], d1[7], e0, e1);
                i32x4 w2 = { c0w, e0, c1, e1 };
                bp[3] = __builtin_bit_cast(bfrag, w2);
            }

            // --- O^T += V^T P : two 32-d tiles x 4 key-steps of 16 ---
#pragma unroll
            for (int ks = 0; ks < 4; ++ks) {
                const int ch = cb + ks * 2 + hi;
                bfrag v0 = *(const bfrag*)&Vs[p][(l32 * 16 + (ch ^ (l32 & 7))) * 8];
                bfrag v1 = *(const bfrag*)&Vs[p][((32 + l32) * 16 + (ch ^ (l32 & 7))) * 8];
                ov0 = __builtin_amdgcn_mfma_f32_32x32x16_bf16(v0, bp[ks], ov0, 0, 0, 0);
                ov1 = __builtin_amdgcn_mfma_f32_32x32x16_bf16(v1, bp[ks], ov1, 0, 0, 0);
            }
        }

        if (more) {
#pragma unroll
            for (int i = 0; i < 4; ++i) {
                *(bfrag*)&Ks[p ^ 1][swzK[i]] = kn[i];
                *(bfrag*)&Vs[p ^ 1][swzV[i]] = vn[i];
            }
            __syncthreads();
        }
    }

    // epilogue: O = O_acc / l, written directly as bf16 [B,S,E]
    // ov reg r -> d = (r&3) + 8*(r>>2) + 4*hi (+32 for ov1), q = l32
    const float inv = 1.f / l_run;
    const size_t orow = ((size_t)b * SEQ + qb + l32) * EMBED + h * HDIM;
#pragma unroll
    for (int rr = 0; rr < 4; ++rr) {
        ushort4 o0, o1;
        o0.x = f2b(ov0[4 * rr + 0] * inv); o0.y = f2b(ov0[4 * rr + 1] * inv);
        o0.z = f2b(ov0[4 * rr + 2] * inv); o0.w = f2b(ov0[4 * rr + 3] * inv);
        o1.x = f2b(ov1[4 * rr + 0] * inv); o1.y = f2b(ov1[4 * rr + 1] * inv);
        o1.z = f2b(ov1[4 * rr + 2] * inv); o1.w = f2b(ov1[4 * rr + 3] * inv);
        *(ushort4*)&ao[orow + rr * 8 + hi * 4] = o0;
        *(ushort4*)&ao[orow + 32 + rr * 8 + hi * 4] = o1;
    }
}

// ---------- launch ----------
extern "C" void kernel_launch(void* const* d_in, const int* in_sizes, int n_in,
                              void* d_out, int out_size, void* d_ws, size_t ws_size,
                              hipStream_t stream) {
    const float* query = (const float*)d_in[0];
    const float* key_  = (const float*)d_in[1];
    const float* value = (const float*)d_in[2];
    const float* Wq    = (const float*)d_in[3];
    const float* Wk    = (const float*)d_in[4];
    const float* Wv    = (const float*)d_in[5];
    const float* Wo    = (const float*)d_in[6];
    float* out = (float*)d_out;

    char* ws = (char*)d_ws;
    const size_t MB = 1024 * 1024;
    u16b* xq  = (u16b*)(ws + 0 * MB);    // 8 MB, dead after proj
    u16b* xk  = (u16b*)(ws + 8 * MB);    // dead after proj
    u16b* xv  = (u16b*)(ws + 16 * MB);   // dead after proj
    u16b* wq  = (u16b*)(ws + 24 * MB);   // dead after orth
    u16b* wk  = (u16b*)(ws + 26 * MB);   // dead after orth
    u16b* wv  = (u16b*)(ws + 28 * MB);   // dead after proj
    u16b* gq  = (u16b*)(ws + 32 * MB);   // dead after orth
    u16b* gk  = (u16b*)(ws + 34 * MB);   // dead after orth
    u16b* wqo = (u16b*)(ws + 36 * MB);   // dead after proj
    u16b* wko = (u16b*)(ws + 38 * MB);   // dead after proj
    u16b* wo  = (u16b*)(ws + 40 * MB);   // live until out-proj
    u16b* qp  = (u16b*)(ws + 44 * MB);   // [B,H,S,64], dead after attn
    u16b* kp  = (u16b*)(ws + 52 * MB);   // dead after attn
    u16b* Vt  = (u16b*)(ws + 60 * MB);   // [B,H,64,S], dead after attn
    u16b* wqt = (u16b*)(ws + 60 * MB);   // inside Vt region: dead after gram, Vt written later
    u16b* wkt = (u16b*)(ws + 62 * MB);
    u16b* ao  = (u16b*)(ws + 0 * MB);    // attn output [B,S,E] bf16 over dead xq

    // 1) unified prep (inputs + weights)
    prep_all<<<dim3(MROWS * EMBED / 1024, 1, 7), dim3(256), 0, stream>>>(
        query, key_, value, Wq, Wk, Wv, Wo,
        xq, xk, xv, wq, wk, wv, wo, wqt, wkt);

    // 2) Grams (z-batched): gq = Wq^T Wq, gk = Wk^T Wk  (GM=3 XCD swizzle)
    {
        GemmPtrs p{};
        p.A[0] = wqt; p.B[0] = wqt; p.Cb[0] = gq; p.scale[0] = 1.f;
        p.A[1] = wkt; p.B[1] = wkt; p.Cb[1] = gk; p.scale[1] = 1.f;
        gemm_big<0, 64, 64, 3><<<dim3(512, 1, 1), dim3(256), 0, stream>>>(
            p, EMBED, EMBED, EMBED);
    }
    // 3) Orth (z-batched): wqo = Wq - Wq*gk, wko = Wk - Wk*gq  (GM=3)
    {
        GemmPtrs p{};
        p.A[0] = wq; p.B[0] = gk; p.D[0] = Wq; p.Cb[0] = wqo;
        p.A[1] = wk; p.B[1] = gq; p.D[1] = Wk; p.Cb[1] = wko;
        gemm_big<1, 64, 64, 3><<<dim3(512, 1, 1), dim3(256), 0, stream>>>(
            p, EMBED, EMBED, EMBED);
    }
    // 4) Projections (z-batched): q,k head-split; V transposed  (GM=1)
    {
        GemmPtrs p{};
        p.A[0] = xq; p.B[0] = wqo; p.Cb[0] = qp; p.scale[0] = SCALE_Q; p.hs[0] = 1;
        p.A[1] = xk; p.B[1] = wko; p.Cb[1] = kp; p.scale[1] = 1.f;     p.hs[1] = 1;
        p.A[2] = xv; p.B[2] = wv;  p.Cb[2] = Vt; p.scale[2] = 1.f;     p.vt[2] = 1;
        gemm_big<0, 128, 128, 1><<<dim3(768, 1, 1), dim3(256), 0, stream>>>(
            p, MROWS, EMBED, EMBED);
    }
    // 5) Attention, no split-K (512 blocks, 1D XCD-swizzled grid), writes ao
    flash_attn9<<<dim3(SEQ / 128 * NHEADS * BATCH, 1, 1), dim3(256), 0, stream>>>(
        qp, kp, Vt, ao);
    // 6) Output projection (fp32 out)  (GM=2)
    {
        GemmPtrs p{};
        p.A[0] = ao; p.B[0] = wo; p.Cf[0] = out; p.scale[0] = 1.f;
        gemm_big<2, 64, 128, 2><<<dim3(512, 1, 1), dim3(256), 0, stream>>>(
            p, MROWS, EMBED, EMBED);
    }
}